// Round 2
// baseline (930.102 us; speedup 1.0000x reference)
//
#include <hip/hip_runtime.h>

#define B_  8
#define N_  16384
#define D_  64
#define S_  2048
#define K_  32
#define SPLIT_  4
#define NSPL_   (N_/SPLIT_)       // 4096 candidates per block
#define CH32_   (NSPL_/32)        // 128 chunks of 32
#define PLANE_  ((size_t)B_*N_*64) // shorts per plane (8.39M = 16.78 MB)

using short8_ = __attribute__((ext_vector_type(8))) short;
using f32x4_  = __attribute__((ext_vector_type(4))) float;

// =====================================================================
// exact bf16 triple-split of fp32 (truncation-based): f = h0 + h1 + h2
// =====================================================================
__device__ __forceinline__ void bf3split(float f, short& h0, short& h1, short& h2)
{
  unsigned u0 = __float_as_uint(f);
  float f0 = __uint_as_float(u0 & 0xFFFF0000u);
  h0 = (short)(u0 >> 16);
  float r1 = f - f0;
  unsigned u1 = __float_as_uint(r1);
  float f1 = __uint_as_float(u1 & 0xFFFF0000u);
  h1 = (short)(u1 >> 16);
  float r2 = r1 - f1;                 // <= 8 significant bits: bf16-exact
  h2 = (short)(__float_as_uint(r2) >> 16);
}

// bf16 2-split of 8 floats (for the MLP; residual ~2^-16 rel)
__device__ __forceinline__ void bf2split8(const float* f, short8_& h0, short8_& h1)
{
  #pragma unroll
  for (int j = 0; j < 8; ++j) {
    unsigned u = __float_as_uint(f[j]);
    h0[j] = (short)(u >> 16);
    float r = f[j] - __uint_as_float(u & 0xFFFF0000u);
    h1[j] = (short)(__float_as_uint(r) >> 16);
  }
}

// sorted-DESCENDING 32-entry list (Lv[0] = largest kept)
__device__ __forceinline__ void insert32(float (&Lv)[32], int (&Li)[32], float x, int n)
{
  bool ci = x < Lv[0];
  #pragma unroll
  for (int i = 0; i < 31; ++i) {
    bool c1 = x < Lv[i+1];
    float nv = c1 ? Lv[i+1] : (ci ? x : Lv[i]);
    int   ni = c1 ? Li[i+1] : (ci ? n : Li[i]);
    Lv[i] = nv; Li[i] = ni;
    ci = c1;
  }
  Lv[31] = ci ? x : Lv[31];
  Li[31] = ci ? n : Li[31];
}

// =====================================================================
// K1 (fast path): sqn + new_xyz gather + fragment-major bf16x3 planes
// sqn: EXACT round-3 expression (bit-identical keys -> selection).
// =====================================================================
__global__ __launch_bounds__(256) void k_prep(
    const float* __restrict__ xyz, const float* __restrict__ points,
    const int* __restrict__ sidx, float* __restrict__ out, float* __restrict__ sqn,
    short* __restrict__ P0, short* __restrict__ P1, short* __restrict__ P2)
{
  int tid = blockIdx.x * 256 + threadIdx.x;      // 0 .. B*N-1
  const float4* p = (const float4*)(points + (size_t)tid * 64);

  float s = 0.f;
  #pragma unroll
  for (int i = 0; i < 16; ++i) {
    float4 v = p[i];
    s += v.x*v.x + v.y*v.y + v.z*v.z + v.w*v.w;
  }
  sqn[tid] = s;

  int n = tid & (N_-1);
  int c = n >> 6, ct = (n >> 4) & 3, mc = n & 15;
  size_t segbase = (((size_t)(tid >> 14) * 256 + c) * 4 + ct) * 2;  // *512 shorts

  #pragma unroll
  for (int g = 0; g < 8; ++g) {                  // (kt=g>>2, qd=g&3), dims 8g..8g+7
    float4 a = p[2*g], b4 = p[2*g+1];
    float f[8] = {a.x,a.y,a.z,a.w, b4.x,b4.y,b4.z,b4.w};
    short8_ h0v, h1v, h2v;
    #pragma unroll
    for (int j = 0; j < 8; ++j) {
      short h0, h1, h2;
      bf3split(f[j], h0, h1, h2);
      h0v[j] = h0; h1v[j] = h1; h2v[j] = h2;
    }
    size_t off = ((segbase + (g>>2))*64 + (size_t)(g&3)*16 + mc)*8;
    *(short8_*)(P0 + off) = h0v;
    *(short8_*)(P1 + off) = h1v;
    *(short8_*)(P2 + off) = h2v;
  }
  if (tid < B_*S_) {
    int b = tid >> 11, ss = tid & (S_-1);
    int nn = sidx[ss];
    const float* src = xyz + ((size_t)b * N_ + nn) * 3;
    out[(size_t)tid*3+0] = src[0];
    out[(size_t)tid*3+1] = src[1];
    out[(size_t)tid*3+2] = src[2];
  }
}

// =====================================================================
// K2 (fast path), r12: VALU-diet on the barrier-free loop.
//  - plane/sqn loads: uniform char* base + 32-bit lane offset (compiler
//    emits s-base global_load, killing per-lane 64-bit address adds)
//  - admission: popc-hoisted capacity drain (single insert32 site) +
//    8 statically-unrolled predicated pushes (no ffs select tree)
//  - thr cached, refreshed every other chunk (stale thr >= fresh thr ->
//    still a valid upper bound -> admitted superset unchanged logic)
//  - s_setprio(1) around the MFMA cluster (barrier-free multi-wave
//    regime: analog of attn case where it measured +4-7%)
// Keys bit-identical to r3..r11; selection superset argument unchanged.
// =====================================================================
__global__ __launch_bounds__(256) void k_knn(
    const short* __restrict__ P0, const short* __restrict__ P1,
    const short* __restrict__ P2, const int* __restrict__ sidx,
    const float* __restrict__ sqn, uint2* __restrict__ pw)
{
  // LDS: Dtr [64r][36c] 9216 | qbuf 16384 @9216 (total 25600)
  // merge phase aliases front as uint2 mbuf[32][130] = 33280 (all dead then)
  __shared__ __align__(16) char smraw[33280];
  float* Dtr = (float*)smraw;
  uint2* qb  = (uint2*)(smraw + 9216);   // [8 slots][256 lanes]

  const int t = threadIdx.x;
  const int b     = blockIdx.x & 7;          // XCD swizzle
  const int y     = blockIdx.x >> 3;
  const int tile  = y & 31;
  const int split = y >> 5;
  const int s0 = tile * 64;

  const int lane = t & 63, wv = t >> 6;
  const int quad = lane >> 4, mcol = lane & 15;

  // ---- A fragments (wave wv owns sampled rows 16*wv..+15), from planes ----
  short8_ A0[2], A1[2], A2[2];
  {
    int srow = sidx[s0 + 16*wv + mcol];
    int cs = srow >> 6, cts = (srow >> 4) & 3, ms = srow & 15;
    size_t ab = (((size_t)(b*256 + cs))*4 + cts)*2*512 + ((size_t)quad*16 + ms)*8;
    #pragma unroll
    for (int kt = 0; kt < 2; ++kt) {
      A0[kt] = *(const short8_*)(P0 + ab + kt*512);
      A1[kt] = *(const short8_*)(P1 + ab + kt*512);
      A2[kt] = *(const short8_*)(P2 + ab + kt*512);
    }
  }

  float Lv[32]; int Li[32];
  #pragma unroll
  for (int i = 0; i < 32; ++i) { Lv[i] = 3.0e38f; Li[i] = 0; }

  const int r = t >> 2;        // selection row 0..63
  const int q = t & 3;         // stream within row
  const int n0base = split * NSPL_;
  const size_t bc8base = (size_t)b * 256;

  int qhead = 0, qtail = 0;    // per-lane FIFO state
  float thr = 3.0e38f;         // cached cross-stream threshold (refresh alt.)

  // uniform byte base of this block's linear plane walk; lane part is 32-bit
  const size_t blkbase = ((bc8base + (size_t)(n0base >> 6)) * 8) * 512 * 2; // bytes
  const char* P0c = (const char*)P0 + blkbase;
  const char* P1c = (const char*)P1 + blkbase;
  const char* P2c = (const char*)P2 + blkbase;
  const char* Qc  = (const char*)(sqn + (size_t)b * N_ + n0base);
  const int lo16 = lane * 16;     // lane byte offset within chunk slot
  const int mo4  = mcol * 4;

  // selection pass for the chunk whose keys sit in Dtr (wave-private rows)
  auto do_select = [&](int n0sel, bool refresh) {
    // ---- adaptive drain: pass only when some lane has >=2 pending ----
    if (__any((qtail - qhead) >= 2)) {
      if (qhead < qtail) {
        uint2 e = qb[(qhead & 7)*256 + t];
        qhead++;
        float x = __uint_as_float(e.x);
        if (x < Lv[0])
          insert32(Lv, Li, x, (int)e.y);
      }
    }
    // ---- cross-stream bounds (refreshed every other chunk; stale = valid) ----
    if (refresh) {
      float tmin = Lv[0];                     // min of stream 32nds
      tmin = fminf(tmin, __shfl_xor(tmin, 1));
      tmin = fminf(tmin, __shfl_xor(tmin, 2));
      float t24 = Lv[24];                     // stream 8th-smallest
      t24 = fmaxf(t24, __shfl_xor(t24, 1));
      t24 = fmaxf(t24, __shfl_xor(t24, 2));   // max over streams: row-32nd <= t24
      thr = fminf(tmin, t24);
    }
    const float th = fminf(thr, Lv[0]);       // per-lane tightener, always fresh

    float4 ka = *(const float4*)(Dtr + r*36 + q*8);
    float4 kb = *(const float4*)(Dtr + r*36 + q*8 + 4);
    float x8[8] = {ka.x,ka.y,ka.z,ka.w, kb.x,kb.y,kb.z,kb.w};
    unsigned m = 0;
    #pragma unroll
    for (int i = 0; i < 8; ++i)
      m |= (x8[i] < th) ? (1u << i) : 0u;

    // ---- make room up-front (single insert32 site), then push statically ----
    int cnt = __popc(m);
    while (__any(qtail - qhead + cnt > 8)) {
      if (qtail - qhead + cnt > 8) {
        uint2 e = qb[(qhead & 7)*256 + t];
        qhead++;
        float xe = __uint_as_float(e.x);
        if (xe < Lv[0])
          insert32(Lv, Li, xe, (int)e.y);
      }
    }
    #pragma unroll
    for (int i = 0; i < 8; ++i) {
      if (m & (1u << i)) {
        qb[(qtail & 7)*256 + t] =
            make_uint2(__float_as_uint(x8[i]), (unsigned)(n0sel + q*8 + i));
        qtail++;
      }
    }
  };

  for (int ch = 0; ch < CH32_; ++ch) {
    const int n0 = n0base + ch * 32;
    const int cb = ch*4096 + lo16;          // chunk byte offset (32-bit, 1 v_add)

    // ---- issue B-fragment loads for chunk ch (s-base + voffset form) ----
    short8_ b0[2][2], b1[2][2], b2[2][2];   // [ct][kt]
    #pragma unroll
    for (int s = 0; s < 4; ++s) {           // s = ct*2 + kt, imm offset s*1024
      b0[s>>1][s&1] = *(const short8_*)(P0c + cb + s*1024);
      b1[s>>1][s&1] = *(const short8_*)(P1c + cb + s*1024);
      b2[s>>1][s&1] = *(const short8_*)(P2c + cb + s*1024);
    }
    const int qo = ch*128 + mo4;
    float sq0 = *(const float*)(Qc + qo);        // ct=0 column sqnorm
    float sq1 = *(const float*)(Qc + qo + 64);   // ct=1 column sqnorm

    // ---- selection for chunk ch-1 (hides the load latency) ----
    if (ch > 0) do_select(n0 - 32, (ch & 1) != 0);

    // ---- 16 MFMA per 16-cand tile (8 combos x 2 kt), 2 tiles ----
    __builtin_amdgcn_s_setprio(1);
    #pragma unroll
    for (int ct = 0; ct < 2; ++ct) {
      f32x4_ a = {0.f, 0.f, 0.f, 0.f};
      #pragma unroll
      for (int kt = 0; kt < 2; ++kt) {
        a = __builtin_amdgcn_mfma_f32_16x16x32_bf16(A0[kt], b0[ct][kt], a, 0,0,0);
        a = __builtin_amdgcn_mfma_f32_16x16x32_bf16(A0[kt], b1[ct][kt], a, 0,0,0);
        a = __builtin_amdgcn_mfma_f32_16x16x32_bf16(A1[kt], b0[ct][kt], a, 0,0,0);
        a = __builtin_amdgcn_mfma_f32_16x16x32_bf16(A1[kt], b1[ct][kt], a, 0,0,0);
        a = __builtin_amdgcn_mfma_f32_16x16x32_bf16(A0[kt], b2[ct][kt], a, 0,0,0);
        a = __builtin_amdgcn_mfma_f32_16x16x32_bf16(A2[kt], b0[ct][kt], a, 0,0,0);
        a = __builtin_amdgcn_mfma_f32_16x16x32_bf16(A1[kt], b2[ct][kt], a, 0,0,0);
        a = __builtin_amdgcn_mfma_f32_16x16x32_bf16(A2[kt], b1[ct][kt], a, 0,0,0);
      }
      // keys -> Dtr (wave-local rows). C/D: col=lane&15, row=quad*4+reg
      int cc = 16*ct + mcol;
      float sq = ct ? sq1 : sq0;
      int rb = 16*wv + 4*quad;
      Dtr[(rb+0)*36 + cc] = sq - 2.f*a[0];
      Dtr[(rb+1)*36 + cc] = sq - 2.f*a[1];
      Dtr[(rb+2)*36 + cc] = sq - 2.f*a[2];
      Dtr[(rb+3)*36 + cc] = sq - 2.f*a[3];
    }
    __builtin_amdgcn_s_setprio(0);
    // no barrier anywhere: Dtr rows 16wv..16wv+15 are wave-private (lgkmcnt)
  }
  do_select(n0base + NSPL_ - 32, true);     // selection for the last chunk

  // ---- final drain ----
  while (__any(qhead < qtail)) {
    if (qhead < qtail) {
      uint2 e = qb[(qhead & 7)*256 + t];
      qhead++;
      float x = __uint_as_float(e.x);
      if (x < Lv[0])
        insert32(Lv, Li, x, (int)e.y);
    }
  }

  // ---- in-block 4-pointer merge (streams stored reversed -> ascending) ----
  uint2* mbuf = (uint2*)smraw;                 // [32][130]
  const int rowg = b * S_ + s0;
  for (int pass = 0; pass < 2; ++pass) {
    __syncthreads();
    const int rb = pass * 32;
    if (r >= rb && r < rb + 32) {
      #pragma unroll
      for (int i = 0; i < 32; ++i)
        mbuf[(r - rb)*130 + q*32 + (31 - i)] =
            make_uint2(__float_as_uint(Lv[i]), (unsigned)Li[i]);
    }
    __syncthreads();
    if (t < 32) {
      const uint2* Lrow = mbuf + t*130;
      uint2* dst = pw + ((size_t)(rowg + rb + t) * SPLIT_ + split) * 32;
      int p0 = 0, p1 = 0, p2 = 0, p3 = 0;
      for (int k = 0; k < 32; ++k) {
        float bv = 3.0e38f; unsigned bi = 0xFFFFFFFFu; int bq = 0;
        int pa[4] = {p0, p1, p2, p3};
        #pragma unroll
        for (int q4 = 0; q4 < 4; ++q4) {
          if (pa[q4] < 32) {
            uint2 e = Lrow[q4*32 + pa[q4]];
            float v = __uint_as_float(e.x);
            if (v < bv || (v == bv && e.y < bi)) { bv = v; bi = e.y; bq = q4; }
          }
        }
        dst[k] = make_uint2(__float_as_uint(bv), bi);
        if (bq == 0) p0++; else if (bq == 1) p1++; else if (bq == 2) p2++; else p3++;
      }
    }
  }
}

// =====================================================================
// FALLBACK path (ws too small): round-3 kernels, proven correct
// =====================================================================
__global__ __launch_bounds__(256) void k_prep_fb(
    const float* __restrict__ xyz, const float* __restrict__ points,
    const int* __restrict__ sidx, float* __restrict__ out, float* __restrict__ sqn)
{
  int tid = blockIdx.x * 256 + threadIdx.x;
  const float4* p = (const float4*)(points + (size_t)tid * 64);
  float s = 0.f;
  #pragma unroll
  for (int i = 0; i < 16; ++i) {
    float4 v = p[i];
    s += v.x*v.x + v.y*v.y + v.z*v.z + v.w*v.w;
  }
  sqn[tid] = s;
  if (tid < B_*S_) {
    int b = tid >> 11, ss = tid & (S_-1);
    int n = sidx[ss];
    const float* src = xyz + ((size_t)b * N_ + n) * 3;
    out[(size_t)tid*3+0] = src[0];
    out[(size_t)tid*3+1] = src[1];
    out[(size_t)tid*3+2] = src[2];
  }
}

__global__ __launch_bounds__(256) void k_knn_fb(
    const float* __restrict__ points, const int* __restrict__ sidx,
    const float* __restrict__ sqn, uint2* __restrict__ pw)
{
  __shared__ __align__(16) char smraw[45312];
  short* Bp0 = (short*)smraw;
  short* Bp1 = (short*)(smraw + 9216);
  short* Bp2 = (short*)(smraw + 18432);
  float* Dt  = (float*)(smraw + 27648);
  float* sqc = (float*)(smraw + 45056);

  const int t = threadIdx.x;
  const int b     = blockIdx.x & 7;
  const int y     = blockIdx.x >> 3;
  const int tile  = y & 31;
  const int split = y >> 5;
  const int s0 = tile * 64;
  const float* Pb = points + (size_t)b * N_ * 64;
  const float* Qb = sqn    + (size_t)b * N_;

  const int lane = t & 63, wv = t >> 6;
  const int quad = lane >> 4, mcol = lane & 15;

  short8_ A0[2], A1[2], A2[2];
  {
    int srow = sidx[s0 + 16*wv + mcol];
    const float* ar = Pb + (size_t)srow * 64;
    #pragma unroll
    for (int kt = 0; kt < 2; ++kt) {
      float4 v0 = *(const float4*)(ar + 32*kt + 8*quad);
      float4 v1 = *(const float4*)(ar + 32*kt + 8*quad + 4);
      float f[8] = {v0.x,v0.y,v0.z,v0.w,v1.x,v1.y,v1.z,v1.w};
      #pragma unroll
      for (int j = 0; j < 8; ++j) {
        short h0, h1, h2;
        bf3split(f[j], h0, h1, h2);
        A0[kt][j] = h0; A1[kt][j] = h1; A2[kt][j] = h2;
      }
    }
  }

  float Lv[32]; int Li[32];
  #pragma unroll
  for (int i = 0; i < 32; ++i) { Lv[i] = 3.0e38f; Li[i] = 0; }

  const int r = t >> 2;
  const int q = t & 3;
  const int n0base = split * NSPL_;

  for (int ch = 0; ch < NSPL_/64; ++ch) {
    const int n0 = n0base + ch * 64;
    {
      const int n = t & 63, jg = t >> 6;
      const float* src = Pb + (size_t)(n0 + n) * 64 + 16*jg;
      float4 u0 = *(const float4*)(src);
      float4 u1 = *(const float4*)(src + 4);
      float4 u2 = *(const float4*)(src + 8);
      float4 u3 = *(const float4*)(src + 12);
      float f[16] = {u0.x,u0.y,u0.z,u0.w, u1.x,u1.y,u1.z,u1.w,
                     u2.x,u2.y,u2.z,u2.w, u3.x,u3.y,u3.z,u3.w};
      short8_ p0[2], p1[2], p2[2];
      #pragma unroll
      for (int j = 0; j < 16; ++j) {
        short h0, h1, h2;
        bf3split(f[j], h0, h1, h2);
        p0[j>>3][j&7] = h0; p1[j>>3][j&7] = h1; p2[j>>3][j&7] = h2;
      }
      *(short8_*)(Bp0 + n*72 + 16*jg)     = p0[0];
      *(short8_*)(Bp0 + n*72 + 16*jg + 8) = p0[1];
      *(short8_*)(Bp1 + n*72 + 16*jg)     = p1[0];
      *(short8_*)(Bp1 + n*72 + 16*jg + 8) = p1[1];
      *(short8_*)(Bp2 + n*72 + 16*jg)     = p2[0];
      *(short8_*)(Bp2 + n*72 + 16*jg + 8) = p2[1];
      if (t < 16) *(float4*)(sqc + 4*t) = *(const float4*)(Qb + n0 + 4*t);
    }
    __syncthreads();

    f32x4_ acc[4];
    #pragma unroll
    for (int ct = 0; ct < 4; ++ct) {
      const int boff = (16*ct + mcol)*72 + 8*quad;
      short8_ b0[2], b1[2], b2[2];
      b0[0] = *(const short8_*)(Bp0 + boff); b0[1] = *(const short8_*)(Bp0 + boff + 32);
      b1[0] = *(const short8_*)(Bp1 + boff); b1[1] = *(const short8_*)(Bp1 + boff + 32);
      b2[0] = *(const short8_*)(Bp2 + boff); b2[1] = *(const short8_*)(Bp2 + boff + 32);
      f32x4_ a = {0.f, 0.f, 0.f, 0.f};
      #pragma unroll
      for (int kt = 0; kt < 2; ++kt) {
        a = __builtin_amdgcn_mfma_f32_16x16x32_bf16(A0[kt], b0[kt], a, 0,0,0);
        a = __builtin_amdgcn_mfma_f32_16x16x32_bf16(A0[kt], b1[kt], a, 0,0,0);
        a = __builtin_amdgcn_mfma_f32_16x16x32_bf16(A1[kt], b0[kt], a, 0,0,0);
        a = __builtin_amdgcn_mfma_f32_16x16x32_bf16(A1[kt], b1[kt], a, 0,0,0);
        a = __builtin_amdgcn_mfma_f32_16x16x32_bf16(A0[kt], b2[kt], a, 0,0,0);
        a = __builtin_amdgcn_mfma_f32_16x16x32_bf16(A2[kt], b0[kt], a, 0,0,0);
        a = __builtin_amdgcn_mfma_f32_16x16x32_bf16(A1[kt], b2[kt], a, 0,0,0);
        a = __builtin_amdgcn_mfma_f32_16x16x32_bf16(A2[kt], b1[kt], a, 0,0,0);
      }
      acc[ct] = a;
    }
    #pragma unroll
    for (int ct = 0; ct < 4; ++ct) {
      int c = 16*ct + mcol;
      float sq = sqc[c];
      float4 kv;
      kv.x = sq - 2.f*acc[ct][0];
      kv.y = sq - 2.f*acc[ct][1];
      kv.z = sq - 2.f*acc[ct][2];
      kv.w = sq - 2.f*acc[ct][3];
      *(float4*)(Dt + c*68 + 16*wv + 4*quad) = kv;
    }
    __syncthreads();

    float L0 = Lv[0];
    L0 = fminf(L0, __shfl_xor(L0, 1));
    L0 = fminf(L0, __shfl_xor(L0, 2));
    const float tau = L0;
    #pragma unroll
    for (int g = 0; g < 4; ++g) {
      #pragma unroll
      for (int u = 0; u < 4; ++u) {
        int c = q*16 + g*4 + u;
        float x = Dt[c*68 + r];
        if (x < fminf(tau, Lv[0]))
          insert32(Lv, Li, x, n0 + c);
      }
    }
  }

  uint2* mbuf = (uint2*)smraw;
  const int rowg = b * S_ + s0;
  for (int pass = 0; pass < 2; ++pass) {
    __syncthreads();
    const int rb = pass * 32;
    if (r >= rb && r < rb + 32) {
      #pragma unroll
      for (int i = 0; i < 32; ++i)
        mbuf[(r - rb)*130 + q*32 + (31 - i)] =
            make_uint2(__float_as_uint(Lv[i]), (unsigned)Li[i]);
    }
    __syncthreads();
    if (t < 32) {
      const uint2* Lrow = mbuf + t*130;
      uint2* dst = pw + ((size_t)(rowg + rb + t) * SPLIT_ + split) * 32;
      int p0 = 0, p1 = 0, p2 = 0, p3 = 0;
      for (int k = 0; k < 32; ++k) {
        float bv = 3.0e38f; unsigned bi = 0xFFFFFFFFu; int bq = 0;
        int pa[4] = {p0, p1, p2, p3};
        #pragma unroll
        for (int q4 = 0; q4 < 4; ++q4) {
          if (pa[q4] < 32) {
            uint2 e = Lrow[q4*32 + pa[q4]];
            float v = __uint_as_float(e.x);
            if (v < bv || (v == bv && e.y < bi)) { bv = v; bi = e.y; bq = q4; }
          }
        }
        dst[k] = make_uint2(__float_as_uint(bv), bi);
        if (bq == 0) p0++; else if (bq == 1) p1++; else if (bq == 2) p2++; else p3++;
      }
    }
  }
}

// =====================================================================
// K2b: merge the 4 split-partials (ascending) per row -> 32 indices
// =====================================================================
__global__ __launch_bounds__(256) void k_sel(const uint2* __restrict__ pw,
                                             int* __restrict__ nbr)
{
  int row = blockIdx.x * 256 + threadIdx.x;       // 0 .. B*S-1
  const uint2* L = pw + (size_t)row * (SPLIT_*32);
  int* dst = nbr + (size_t)row * K_;
  int p[4] = {0,0,0,0};
  for (int k = 0; k < K_; ++k) {
    float bv = 3.0e38f; unsigned bi = 0xFFFFFFFFu; int bq = 0;
    #pragma unroll
    for (int q4 = 0; q4 < 4; ++q4) {
      if (p[q4] < 32) {
        uint2 e = L[q4*32 + p[q4]];
        float v = __uint_as_float(e.x);
        if (v < bv || (v == bv && e.y < bi)) { bv = v; bi = e.y; bq = q4; }
      }
    }
    dst[k] = (int)bi;
    p[bq]++;
  }
}

// =====================================================================
// K3: MFMA MLP (bf16 2-split) + fused bias/relu/maxpool.
// =====================================================================
__device__ __forceinline__ void layer_mfma(
    int lane, int wv, const float* Xf, float* Hf,
    const float* __restrict__ wgt, const float* scl, const float* bia)
{
  const int quad = lane >> 4, mcol = lane & 15;
  const int o = wv*16 + mcol;                 // this wave's output column
  const float sc = scl[o];
  short8_ B0[2], B1[2];
  #pragma unroll
  for (int kt = 0; kt < 2; ++kt) {
    const float* wp = wgt + o*64 + kt*32 + quad*8;
    float4 u0 = *(const float4*)(wp);
    float4 u1 = *(const float4*)(wp + 4);
    float f[8] = {u0.x*sc,u0.y*sc,u0.z*sc,u0.w*sc,
                  u1.x*sc,u1.y*sc,u1.z*sc,u1.w*sc};
    bf2split8(f, B0[kt], B1[kt]);
  }
  const float bo = bia[o];
  const int kt2 = (o >> 5) & 1, qk2 = (o >> 3) & 3, h2 = (o >> 2) & 1, j2 = o & 3;
  #pragma unroll
  for (int mt = 0; mt < 2; ++mt) {
    short8_ A0[2], A1[2];
    #pragma unroll
    for (int kt = 0; kt < 2; ++kt) {
      float4 x0 = *(const float4*)(Xf + (((mt*2+kt)*2+0)*256) + lane*4);
      float4 x1 = *(const float4*)(Xf + (((mt*2+kt)*2+1)*256) + lane*4);
      float f[8] = {x0.x,x0.y,x0.z,x0.w, x1.x,x1.y,x1.z,x1.w};
      bf2split8(f, A0[kt], A1[kt]);
    }
    f32x4_ a = {0.f, 0.f, 0.f, 0.f};
    #pragma unroll
    for (int kt = 0; kt < 2; ++kt) {
      a = __builtin_amdgcn_mfma_f32_16x16x32_bf16(A0[kt], B0[kt], a, 0,0,0);
      a = __builtin_amdgcn_mfma_f32_16x16x32_bf16(A0[kt], B1[kt], a, 0,0,0);
      a = __builtin_amdgcn_mfma_f32_16x16x32_bf16(A1[kt], B0[kt], a, 0,0,0);
    }
    #pragma unroll
    for (int reg = 0; reg < 4; ++reg) {
      int ml = quad*4 + reg;                  // m within mtile
      float hval = fmaxf(a[reg] + bo, 0.f);
      Hf[((mt*2 + kt2)*2 + h2)*256 + (qk2*16 + ml)*4 + j2] = hval;
    }
  }
}

__global__ __launch_bounds__(256) void k_mlp(
    const float* __restrict__ points, const int* __restrict__ nbr,
    const float* __restrict__ w0, const float* __restrict__ b0,
    const float* __restrict__ g0, const float* __restrict__ be0,
    const float* __restrict__ m0, const float* __restrict__ v0,
    const float* __restrict__ w1, const float* __restrict__ b1,
    const float* __restrict__ g1, const float* __restrict__ be1,
    const float* __restrict__ m1, const float* __restrict__ v1,
    const float* __restrict__ w2, const float* __restrict__ b2,
    const float* __restrict__ g2, const float* __restrict__ be2,
    const float* __restrict__ m2, const float* __restrict__ v2,
    float* __restrict__ out)
{
  __shared__ __align__(16) float Xf[2048];   // 8 segs x 1KB
  __shared__ __align__(16) float Hf[2048];
  __shared__ float scl[128];
  __shared__ float bia[128];
  __shared__ int   nIx[32];

  const int t  = threadIdx.x;
  const int bs = blockIdx.x;
  const int b  = bs >> 11;
  const int lane = t & 63, wv = t >> 6;
  const int quad = lane >> 4, mcol = lane & 15;

  if (t < 32) nIx[t] = nbr[(size_t)bs * K_ + t];
  if (t >= 64 && t < 128) {                  // layer-0 BN fold in parallel
    int i = t - 64;
    float sc = g0[i] * rsqrtf(v0[i] + 1e-5f);
    scl[i] = sc;
    bia[i] = (b0[i] - m0[i]) * sc + be0[i];
  }
  __syncthreads();
  // stage X (32 rows x 64 ch fp32) into fragment-major segments
  #pragma unroll
  for (int rep = 0; rep < 2; ++rep) {
    int task = rep*256 + t;
    int row = task >> 4, j4 = task & 15;
    float4 v = *(const float4*)(points + ((size_t)b*N_ + nIx[row])*64 + j4*4);
    int kt = j4 >> 3, qk = (j4 >> 1) & 3, h = j4 & 1;
    *(float4*)(Xf + (((row>>4)*2 + kt)*2 + h)*256 + (qk*16 + (row&15))*4) = v;
  }
  __syncthreads();

  layer_mfma(lane, wv, Xf, Hf, w0, scl, bia);      // X -> H
  __syncthreads();
  if (t < 64) {
    float sc = g1[t] * rsqrtf(v1[t] + 1e-5f);
    scl[t] = sc;
    bia[t] = (b1[t] - m1[t]) * sc + be1[t];
  }
  __syncthreads();
  layer_mfma(lane, wv, Hf, Xf, w1, scl, bia);      // H -> X
  __syncthreads();
  if (t < 128) {
    float sc = g2[t] * rsqrtf(v2[t] + 1e-5f);
    scl[t] = sc;
    bia[t] = (b2[t] - m2[t]) * sc + be2[t];
  }
  __syncthreads();

  // ---- layer 2: 64 -> 128, fused maxpool.  A-frags hoisted ----
  short8_ A0[2][2], A1[2][2];
  #pragma unroll
  for (int mt = 0; mt < 2; ++mt)
    #pragma unroll
    for (int kt = 0; kt < 2; ++kt) {
      float4 x0 = *(const float4*)(Xf + (((mt*2+kt)*2+0)*256) + lane*4);
      float4 x1 = *(const float4*)(Xf + (((mt*2+kt)*2+1)*256) + lane*4);
      float f[8] = {x0.x,x0.y,x0.z,x0.w, x1.x,x1.y,x1.z,x1.w};
      bf2split8(f, A0[mt][kt], A1[mt][kt]);
    }
  float* outp = out + (size_t)(B_*S_)*3 + (size_t)bs*128;
  #pragma unroll
  for (int sub = 0; sub < 2; ++sub) {
    const int o = (wv*2 + sub)*16 + mcol;
    const float sc = scl[o];
    short8_ B0[2], B1[2];
    #pragma unroll
    for (int kt = 0; kt < 2; ++kt) {
      const float* wp = w2 + o*64 + kt*32 + quad*8;
      float4 u0 = *(const float4*)(wp);
      float4 u1 = *(const float4*)(wp + 4);
      float f[8] = {u0.x*sc,u0.y*sc,u0.z*sc,u0.w*sc,
                    u1.x*sc,u1.y*sc,u1.z*sc,u1.w*sc};
      bf2split8(f, B0[kt], B1[kt]);
    }
    float vmax = -3.0e38f;
    #pragma unroll
    for (int mt = 0; mt < 2; ++mt) {
      f32x4_ a = {0.f, 0.f, 0.f, 0.f};
      #pragma unroll
      for (int kt = 0; kt < 2; ++kt) {
        a = __builtin_amdgcn_mfma_f32_16x16x32_bf16(A0[mt][kt], B0[kt], a, 0,0,0);
        a = __builtin_amdgcn_mfma_f32_16x16x32_bf16(A0[mt][kt], B1[kt], a, 0,0,0);
        a = __builtin_amdgcn_mfma_f32_16x16x32_bf16(A1[mt][kt], B0[kt], a, 0,0,0);
      }
      vmax = fmaxf(vmax, fmaxf(fmaxf(a[0], a[1]), fmaxf(a[2], a[3])));
    }
    vmax = fmaxf(vmax, __shfl_xor(vmax, 16));
    vmax = fmaxf(vmax, __shfl_xor(vmax, 32));
    if (quad == 0) outp[o] = fmaxf(vmax + bia[o], 0.f);
  }
}

// =====================================================================
extern "C" void kernel_launch(void* const* d_in, const int* in_sizes, int n_in,
                              void* d_out, int out_size, void* d_ws, size_t ws_size,
                              hipStream_t stream)
{
  const float* xyz  = (const float*)d_in[0];
  const float* pts  = (const float*)d_in[1];
  const int*   sidx = (const int*)  d_in[2];
  const float* w0 = (const float*)d_in[3];
  const float* b0 = (const float*)d_in[4];
  const float* g0 = (const float*)d_in[5];
  const float* be0= (const float*)d_in[6];
  const float* m0 = (const float*)d_in[7];
  const float* v0 = (const float*)d_in[8];
  const float* w1 = (const float*)d_in[9];
  const float* b1 = (const float*)d_in[10];
  const float* g1 = (const float*)d_in[11];
  const float* be1= (const float*)d_in[12];
  const float* m1 = (const float*)d_in[13];
  const float* v1 = (const float*)d_in[14];
  const float* w2 = (const float*)d_in[15];
  const float* b2 = (const float*)d_in[16];
  const float* g2 = (const float*)d_in[17];
  const float* be2= (const float*)d_in[18];
  const float* m2 = (const float*)d_in[19];
  const float* v2 = (const float*)d_in[20];

  float* out = (float*)d_out;
  // ws: sqn (512KB) | nbr (2MB) | pw (16.8MB) | planes (3 x 16.78MB)
  float* sqn = (float*)d_ws;
  int*   nbr = (int*)  ((char*)d_ws + (size_t)B_*N_*4);
  uint2* pw  = (uint2*)((char*)d_ws + (size_t)B_*N_*4 + (size_t)B_*S_*K_*4);
  char*  pl  = (char*)d_ws + (size_t)B_*N_*4 + (size_t)B_*S_*K_*4
             + (size_t)B_*S_*SPLIT_*32*8;
  short* P0 = (short*)pl;
  short* P1 = P0 + PLANE_;
  short* P2 = P1 + PLANE_;
  const size_t need = (size_t)B_*N_*4 + (size_t)B_*S_*K_*4
                    + (size_t)B_*S_*SPLIT_*32*8 + 3*PLANE_*2;

  if (ws_size >= need) {
    k_prep<<<(B_*N_)/256, 256, 0, stream>>>(xyz, pts, sidx, out, sqn, P0, P1, P2);
    k_knn <<<B_*32*SPLIT_, 256, 0, stream>>>(P0, P1, P2, sidx, sqn, pw);
  } else {
    k_prep_fb<<<(B_*N_)/256, 256, 0, stream>>>(xyz, pts, sidx, out, sqn);
    k_knn_fb <<<B_*32*SPLIT_, 256, 0, stream>>>(pts, sidx, sqn, pw);
  }
  k_sel <<<(B_*S_)/256, 256, 0, stream>>>(pw, nbr);
  k_mlp <<<B_*S_, 256, 0, stream>>>(pts, nbr,
            w0,b0,g0,be0,m0,v0, w1,b1,g1,be1,m1,v1, w2,b2,g2,be2,m2,v2, out);
}

// Round 3
// 792.191 us; speedup vs baseline: 1.1741x; 1.1741x over previous
//
#include <hip/hip_runtime.h>

#define B_  8
#define N_  16384
#define D_  64
#define S_  2048
#define K_  32
#define SPLIT_  4
#define NSPL_   (N_/SPLIT_)       // 4096 candidates per block
#define CH32_   (NSPL_/32)        // 128 chunks of 32
#define PLANE_  ((size_t)B_*N_*64) // shorts per plane (8.39M = 16.78 MB)

using short8_ = __attribute__((ext_vector_type(8))) short;
using f32x4_  = __attribute__((ext_vector_type(4))) float;

// =====================================================================
// exact bf16 triple-split of fp32 (truncation-based): f = h0 + h1 + h2
// =====================================================================
__device__ __forceinline__ void bf3split(float f, short& h0, short& h1, short& h2)
{
  unsigned u0 = __float_as_uint(f);
  float f0 = __uint_as_float(u0 & 0xFFFF0000u);
  h0 = (short)(u0 >> 16);
  float r1 = f - f0;
  unsigned u1 = __float_as_uint(r1);
  float f1 = __uint_as_float(u1 & 0xFFFF0000u);
  h1 = (short)(u1 >> 16);
  float r2 = r1 - f1;                 // <= 8 significant bits: bf16-exact
  h2 = (short)(__float_as_uint(r2) >> 16);
}

// bf16 2-split of 8 floats (for the MLP; residual ~2^-16 rel)
__device__ __forceinline__ void bf2split8(const float* f, short8_& h0, short8_& h1)
{
  #pragma unroll
  for (int j = 0; j < 8; ++j) {
    unsigned u = __float_as_uint(f[j]);
    h0[j] = (short)(u >> 16);
    float r = f[j] - __uint_as_float(u & 0xFFFF0000u);
    h1[j] = (short)(__float_as_uint(r) >> 16);
  }
}

// sorted-DESCENDING 32-entry list (Lv[0] = largest kept)
__device__ __forceinline__ void insert32(float (&Lv)[32], int (&Li)[32], float x, int n)
{
  bool ci = x < Lv[0];
  #pragma unroll
  for (int i = 0; i < 31; ++i) {
    bool c1 = x < Lv[i+1];
    float nv = c1 ? Lv[i+1] : (ci ? x : Lv[i]);
    int   ni = c1 ? Li[i+1] : (ci ? n : Li[i]);
    Lv[i] = nv; Li[i] = ni;
    ci = c1;
  }
  Lv[31] = ci ? x : Lv[31];
  Li[31] = ci ? n : Li[31];
}

// =====================================================================
// K1 (fast path): sqn + new_xyz gather + fragment-major bf16x3 planes
// sqn: EXACT round-3 expression (bit-identical keys -> selection).
// =====================================================================
__global__ __launch_bounds__(256) void k_prep(
    const float* __restrict__ xyz, const float* __restrict__ points,
    const int* __restrict__ sidx, float* __restrict__ out, float* __restrict__ sqn,
    short* __restrict__ P0, short* __restrict__ P1, short* __restrict__ P2)
{
  int tid = blockIdx.x * 256 + threadIdx.x;      // 0 .. B*N-1
  const float4* p = (const float4*)(points + (size_t)tid * 64);

  float s = 0.f;
  #pragma unroll
  for (int i = 0; i < 16; ++i) {
    float4 v = p[i];
    s += v.x*v.x + v.y*v.y + v.z*v.z + v.w*v.w;
  }
  sqn[tid] = s;

  int n = tid & (N_-1);
  int c = n >> 6, ct = (n >> 4) & 3, mc = n & 15;
  size_t segbase = (((size_t)(tid >> 14) * 256 + c) * 4 + ct) * 2;  // *512 shorts

  #pragma unroll
  for (int g = 0; g < 8; ++g) {                  // (kt=g>>2, qd=g&3), dims 8g..8g+7
    float4 a = p[2*g], b4 = p[2*g+1];
    float f[8] = {a.x,a.y,a.z,a.w, b4.x,b4.y,b4.z,b4.w};
    short8_ h0v, h1v, h2v;
    #pragma unroll
    for (int j = 0; j < 8; ++j) {
      short h0, h1, h2;
      bf3split(f[j], h0, h1, h2);
      h0v[j] = h0; h1v[j] = h1; h2v[j] = h2;
    }
    size_t off = ((segbase + (g>>2))*64 + (size_t)(g&3)*16 + mc)*8;
    *(short8_*)(P0 + off) = h0v;
    *(short8_*)(P1 + off) = h1v;
    *(short8_*)(P2 + off) = h2v;
  }
  if (tid < B_*S_) {
    int b = tid >> 11, ss = tid & (S_-1);
    int nn = sidx[ss];
    const float* src = xyz + ((size_t)b * N_ + nn) * 3;
    out[(size_t)tid*3+0] = src[0];
    out[(size_t)tid*3+1] = src[1];
    out[(size_t)tid*3+2] = src[2];
  }
}

// =====================================================================
// K2 (fast path), r13 == r11 exact revert: BARRIER-FREE main loop.
// (r12's VALU-diet bundle regressed: stale-thr admissions + unrolled
// push machinery + setprio added ~58% VALU work.  Reverted verbatim.)
// Keys bit-identical to r3..r11; selection superset argument unchanged.
// =====================================================================
__global__ __launch_bounds__(256) void k_knn(
    const short* __restrict__ P0, const short* __restrict__ P1,
    const short* __restrict__ P2, const int* __restrict__ sidx,
    const float* __restrict__ sqn, uint2* __restrict__ pw)
{
  // LDS: Dtr [64r][36c] 9216 | qbuf 16384 @9216 (total 25600)
  // merge phase aliases front as uint2 mbuf[32][130] = 33280 (all dead then)
  __shared__ __align__(16) char smraw[33280];
  float* Dtr = (float*)smraw;
  uint2* qb  = (uint2*)(smraw + 9216);   // [8 slots][256 lanes]

  const int t = threadIdx.x;
  const int b     = blockIdx.x & 7;          // XCD swizzle
  const int y     = blockIdx.x >> 3;
  const int tile  = y & 31;
  const int split = y >> 5;
  const int s0 = tile * 64;
  const float* Qb = sqn + (size_t)b * N_;

  const int lane = t & 63, wv = t >> 6;
  const int quad = lane >> 4, mcol = lane & 15;

  // ---- A fragments (wave wv owns sampled rows 16*wv..+15), from planes ----
  short8_ A0[2], A1[2], A2[2];
  {
    int srow = sidx[s0 + 16*wv + mcol];
    int cs = srow >> 6, cts = (srow >> 4) & 3, ms = srow & 15;
    size_t ab = (((size_t)(b*256 + cs))*4 + cts)*2*512 + ((size_t)quad*16 + ms)*8;
    #pragma unroll
    for (int kt = 0; kt < 2; ++kt) {
      A0[kt] = *(const short8_*)(P0 + ab + kt*512);
      A1[kt] = *(const short8_*)(P1 + ab + kt*512);
      A2[kt] = *(const short8_*)(P2 + ab + kt*512);
    }
  }

  float Lv[32]; int Li[32];
  #pragma unroll
  for (int i = 0; i < 32; ++i) { Lv[i] = 3.0e38f; Li[i] = 0; }

  const int r = t >> 2;        // selection row 0..63
  const int q = t & 3;         // stream within row
  const int n0base = split * NSPL_;
  const size_t bc8base = (size_t)b * 256;

  int qhead = 0, qtail = 0;    // per-lane FIFO state

  // selection pass for the chunk whose keys sit in Dtr (wave-private rows)
  auto do_select = [&](int n0sel) {
    // ---- adaptive drain: pass only when some lane has >=2 pending ----
    if (__any((qtail - qhead) >= 2)) {
      if (qhead < qtail) {
        uint2 e = qb[(qhead & 7)*256 + t];
        qhead++;
        float x = __uint_as_float(e.x);
        if (x < Lv[0])
          insert32(Lv, Li, x, (int)e.y);
      }
    }
    // ---- admission: dual exact bounds, cheap FIFO pushes ----
    float ownL0 = Lv[0];
    float tmin = ownL0;                       // min of stream 32nds
    tmin = fminf(tmin, __shfl_xor(tmin, 1));
    tmin = fminf(tmin, __shfl_xor(tmin, 2));
    float t24 = Lv[24];                       // stream 8th-smallest
    t24 = fmaxf(t24, __shfl_xor(t24, 1));
    t24 = fmaxf(t24, __shfl_xor(t24, 2));     // max over streams: row-32nd <= t24
    const float thr = fminf(fminf(tmin, t24), ownL0);

    float4 ka = *(const float4*)(Dtr + r*36 + q*8);
    float4 kb = *(const float4*)(Dtr + r*36 + q*8 + 4);
    float x8[8] = {ka.x,ka.y,ka.z,ka.w, kb.x,kb.y,kb.z,kb.w};
    unsigned m = 0;
    #pragma unroll
    for (int i = 0; i < 8; ++i)
      m |= (x8[i] < thr) ? (1u << i) : 0u;
    while (m) {                               // per-lane, cheap body
      int i = __ffs(m) - 1;
      m &= m - 1;
      float xlo = (i & 1) ? ((i & 2) ? x8[3] : x8[1]) : ((i & 2) ? x8[2] : x8[0]);
      float xhi = (i & 1) ? ((i & 2) ? x8[7] : x8[5]) : ((i & 2) ? x8[6] : x8[4]);
      float x = (i & 4) ? xhi : xlo;
      if (qtail - qhead >= 8) {               // full: drain one in-place (rare)
        uint2 e = qb[(qhead & 7)*256 + t];
        qhead++;
        float xe = __uint_as_float(e.x);
        if (xe < Lv[0])
          insert32(Lv, Li, xe, (int)e.y);
      }
      qb[(qtail & 7)*256 + t] = make_uint2(__float_as_uint(x), (unsigned)(n0sel + q*8 + i));
      qtail++;
    }
  };

  // running plane offset for chunk 0 ((n0base>>5)&1 == 0: n0base % 64 == 0)
  size_t goff = ((bc8base + (size_t)(n0base >> 6)) * 8) * 512 + (size_t)lane * 8;

  for (int ch = 0; ch < CH32_; ++ch) {
    const int n0 = n0base + ch * 32;

    // ---- issue B-fragment loads for chunk ch (direct from planes, L2/L3) ----
    short8_ b0[2][2], b1[2][2], b2[2][2];   // [ct][kt]
    #pragma unroll
    for (int s = 0; s < 4; ++s) {           // s = ct*2 + kt
      b0[s>>1][s&1] = *(const short8_*)(P0 + goff + (size_t)s*512);
      b1[s>>1][s&1] = *(const short8_*)(P1 + goff + (size_t)s*512);
      b2[s>>1][s&1] = *(const short8_*)(P2 + goff + (size_t)s*512);
    }
    float sq0 = Qb[n0 + mcol];              // ct=0 column sqnorm
    float sq1 = Qb[n0 + 16 + mcol];         // ct=1 column sqnorm
    goff += 2048;                           // 4 slots x 512 shorts per chunk

    // ---- selection for chunk ch-1 (hides the load latency) ----
    if (ch > 0) do_select(n0 - 32);

    // ---- 16 MFMA per 16-cand tile (8 combos x 2 kt), 2 tiles ----
    #pragma unroll
    for (int ct = 0; ct < 2; ++ct) {
      f32x4_ a = {0.f, 0.f, 0.f, 0.f};
      #pragma unroll
      for (int kt = 0; kt < 2; ++kt) {
        a = __builtin_amdgcn_mfma_f32_16x16x32_bf16(A0[kt], b0[ct][kt], a, 0,0,0);
        a = __builtin_amdgcn_mfma_f32_16x16x32_bf16(A0[kt], b1[ct][kt], a, 0,0,0);
        a = __builtin_amdgcn_mfma_f32_16x16x32_bf16(A1[kt], b0[ct][kt], a, 0,0,0);
        a = __builtin_amdgcn_mfma_f32_16x16x32_bf16(A1[kt], b1[ct][kt], a, 0,0,0);
        a = __builtin_amdgcn_mfma_f32_16x16x32_bf16(A0[kt], b2[ct][kt], a, 0,0,0);
        a = __builtin_amdgcn_mfma_f32_16x16x32_bf16(A2[kt], b0[ct][kt], a, 0,0,0);
        a = __builtin_amdgcn_mfma_f32_16x16x32_bf16(A1[kt], b2[ct][kt], a, 0,0,0);
        a = __builtin_amdgcn_mfma_f32_16x16x32_bf16(A2[kt], b1[ct][kt], a, 0,0,0);
      }
      // keys -> Dtr (wave-local rows). C/D: col=lane&15, row=quad*4+reg
      int cc = 16*ct + mcol;
      float sq = ct ? sq1 : sq0;
      int rb = 16*wv + 4*quad;
      Dtr[(rb+0)*36 + cc] = sq - 2.f*a[0];
      Dtr[(rb+1)*36 + cc] = sq - 2.f*a[1];
      Dtr[(rb+2)*36 + cc] = sq - 2.f*a[2];
      Dtr[(rb+3)*36 + cc] = sq - 2.f*a[3];
    }
    // no barrier anywhere: Dtr rows 16wv..16wv+15 are wave-private (lgkmcnt)
  }
  do_select(n0base + NSPL_ - 32);           // selection for the last chunk

  // ---- final drain ----
  while (__any(qhead < qtail)) {
    if (qhead < qtail) {
      uint2 e = qb[(qhead & 7)*256 + t];
      qhead++;
      float x = __uint_as_float(e.x);
      if (x < Lv[0])
        insert32(Lv, Li, x, (int)e.y);
    }
  }

  // ---- in-block 4-pointer merge (streams stored reversed -> ascending) ----
  uint2* mbuf = (uint2*)smraw;                 // [32][130]
  const int rowg = b * S_ + s0;
  for (int pass = 0; pass < 2; ++pass) {
    __syncthreads();
    const int rb = pass * 32;
    if (r >= rb && r < rb + 32) {
      #pragma unroll
      for (int i = 0; i < 32; ++i)
        mbuf[(r - rb)*130 + q*32 + (31 - i)] =
            make_uint2(__float_as_uint(Lv[i]), (unsigned)Li[i]);
    }
    __syncthreads();
    if (t < 32) {
      const uint2* Lrow = mbuf + t*130;
      uint2* dst = pw + ((size_t)(rowg + rb + t) * SPLIT_ + split) * 32;
      int p0 = 0, p1 = 0, p2 = 0, p3 = 0;
      for (int k = 0; k < 32; ++k) {
        float bv = 3.0e38f; unsigned bi = 0xFFFFFFFFu; int bq = 0;
        int pa[4] = {p0, p1, p2, p3};
        #pragma unroll
        for (int q4 = 0; q4 < 4; ++q4) {
          if (pa[q4] < 32) {
            uint2 e = Lrow[q4*32 + pa[q4]];
            float v = __uint_as_float(e.x);
            if (v < bv || (v == bv && e.y < bi)) { bv = v; bi = e.y; bq = q4; }
          }
        }
        dst[k] = make_uint2(__float_as_uint(bv), bi);
        if (bq == 0) p0++; else if (bq == 1) p1++; else if (bq == 2) p2++; else p3++;
      }
    }
  }
}

// =====================================================================
// FALLBACK path (ws too small): round-3 kernels, proven correct
// =====================================================================
__global__ __launch_bounds__(256) void k_prep_fb(
    const float* __restrict__ xyz, const float* __restrict__ points,
    const int* __restrict__ sidx, float* __restrict__ out, float* __restrict__ sqn)
{
  int tid = blockIdx.x * 256 + threadIdx.x;
  const float4* p = (const float4*)(points + (size_t)tid * 64);
  float s = 0.f;
  #pragma unroll
  for (int i = 0; i < 16; ++i) {
    float4 v = p[i];
    s += v.x*v.x + v.y*v.y + v.z*v.z + v.w*v.w;
  }
  sqn[tid] = s;
  if (tid < B_*S_) {
    int b = tid >> 11, ss = tid & (S_-1);
    int n = sidx[ss];
    const float* src = xyz + ((size_t)b * N_ + n) * 3;
    out[(size_t)tid*3+0] = src[0];
    out[(size_t)tid*3+1] = src[1];
    out[(size_t)tid*3+2] = src[2];
  }
}

__global__ __launch_bounds__(256) void k_knn_fb(
    const float* __restrict__ points, const int* __restrict__ sidx,
    const float* __restrict__ sqn, uint2* __restrict__ pw)
{
  __shared__ __align__(16) char smraw[45312];
  short* Bp0 = (short*)smraw;
  short* Bp1 = (short*)(smraw + 9216);
  short* Bp2 = (short*)(smraw + 18432);
  float* Dt  = (float*)(smraw + 27648);
  float* sqc = (float*)(smraw + 45056);

  const int t = threadIdx.x;
  const int b     = blockIdx.x & 7;
  const int y     = blockIdx.x >> 3;
  const int tile  = y & 31;
  const int split = y >> 5;
  const int s0 = tile * 64;
  const float* Pb = points + (size_t)b * N_ * 64;
  const float* Qb = sqn    + (size_t)b * N_;

  const int lane = t & 63, wv = t >> 6;
  const int quad = lane >> 4, mcol = lane & 15;

  short8_ A0[2], A1[2], A2[2];
  {
    int srow = sidx[s0 + 16*wv + mcol];
    const float* ar = Pb + (size_t)srow * 64;
    #pragma unroll
    for (int kt = 0; kt < 2; ++kt) {
      float4 v0 = *(const float4*)(ar + 32*kt + 8*quad);
      float4 v1 = *(const float4*)(ar + 32*kt + 8*quad + 4);
      float f[8] = {v0.x,v0.y,v0.z,v0.w,v1.x,v1.y,v1.z,v1.w};
      #pragma unroll
      for (int j = 0; j < 8; ++j) {
        short h0, h1, h2;
        bf3split(f[j], h0, h1, h2);
        A0[kt][j] = h0; A1[kt][j] = h1; A2[kt][j] = h2;
      }
    }
  }

  float Lv[32]; int Li[32];
  #pragma unroll
  for (int i = 0; i < 32; ++i) { Lv[i] = 3.0e38f; Li[i] = 0; }

  const int r = t >> 2;
  const int q = t & 3;
  const int n0base = split * NSPL_;

  for (int ch = 0; ch < NSPL_/64; ++ch) {
    const int n0 = n0base + ch * 64;
    {
      const int n = t & 63, jg = t >> 6;
      const float* src = Pb + (size_t)(n0 + n) * 64 + 16*jg;
      float4 u0 = *(const float4*)(src);
      float4 u1 = *(const float4*)(src + 4);
      float4 u2 = *(const float4*)(src + 8);
      float4 u3 = *(const float4*)(src + 12);
      float f[16] = {u0.x,u0.y,u0.z,u0.w, u1.x,u1.y,u1.z,u1.w,
                     u2.x,u2.y,u2.z,u2.w, u3.x,u3.y,u3.z,u3.w};
      short8_ p0[2], p1[2], p2[2];
      #pragma unroll
      for (int j = 0; j < 16; ++j) {
        short h0, h1, h2;
        bf3split(f[j], h0, h1, h2);
        p0[j>>3][j&7] = h0; p1[j>>3][j&7] = h1; p2[j>>3][j&7] = h2;
      }
      *(short8_*)(Bp0 + n*72 + 16*jg)     = p0[0];
      *(short8_*)(Bp0 + n*72 + 16*jg + 8) = p0[1];
      *(short8_*)(Bp1 + n*72 + 16*jg)     = p1[0];
      *(short8_*)(Bp1 + n*72 + 16*jg + 8) = p1[1];
      *(short8_*)(Bp2 + n*72 + 16*jg)     = p2[0];
      *(short8_*)(Bp2 + n*72 + 16*jg + 8) = p2[1];
      if (t < 16) *(float4*)(sqc + 4*t) = *(const float4*)(Qb + n0 + 4*t);
    }
    __syncthreads();

    f32x4_ acc[4];
    #pragma unroll
    for (int ct = 0; ct < 4; ++ct) {
      const int boff = (16*ct + mcol)*72 + 8*quad;
      short8_ b0[2], b1[2], b2[2];
      b0[0] = *(const short8_*)(Bp0 + boff); b0[1] = *(const short8_*)(Bp0 + boff + 32);
      b1[0] = *(const short8_*)(Bp1 + boff); b1[1] = *(const short8_*)(Bp1 + boff + 32);
      b2[0] = *(const short8_*)(Bp2 + boff); b2[1] = *(const short8_*)(Bp2 + boff + 32);
      f32x4_ a = {0.f, 0.f, 0.f, 0.f};
      #pragma unroll
      for (int kt = 0; kt < 2; ++kt) {
        a = __builtin_amdgcn_mfma_f32_16x16x32_bf16(A0[kt], b0[kt], a, 0,0,0);
        a = __builtin_amdgcn_mfma_f32_16x16x32_bf16(A0[kt], b1[kt], a, 0,0,0);
        a = __builtin_amdgcn_mfma_f32_16x16x32_bf16(A1[kt], b0[kt], a, 0,0,0);
        a = __builtin_amdgcn_mfma_f32_16x16x32_bf16(A1[kt], b1[kt], a, 0,0,0);
        a = __builtin_amdgcn_mfma_f32_16x16x32_bf16(A0[kt], b2[kt], a, 0,0,0);
        a = __builtin_amdgcn_mfma_f32_16x16x32_bf16(A2[kt], b0[kt], a, 0,0,0);
        a = __builtin_amdgcn_mfma_f32_16x16x32_bf16(A1[kt], b2[kt], a, 0,0,0);
        a = __builtin_amdgcn_mfma_f32_16x16x32_bf16(A2[kt], b1[kt], a, 0,0,0);
      }
      acc[ct] = a;
    }
    #pragma unroll
    for (int ct = 0; ct < 4; ++ct) {
      int c = 16*ct + mcol;
      float sq = sqc[c];
      float4 kv;
      kv.x = sq - 2.f*acc[ct][0];
      kv.y = sq - 2.f*acc[ct][1];
      kv.z = sq - 2.f*acc[ct][2];
      kv.w = sq - 2.f*acc[ct][3];
      *(float4*)(Dt + c*68 + 16*wv + 4*quad) = kv;
    }
    __syncthreads();

    float L0 = Lv[0];
    L0 = fminf(L0, __shfl_xor(L0, 1));
    L0 = fminf(L0, __shfl_xor(L0, 2));
    const float tau = L0;
    #pragma unroll
    for (int g = 0; g < 4; ++g) {
      #pragma unroll
      for (int u = 0; u < 4; ++u) {
        int c = q*16 + g*4 + u;
        float x = Dt[c*68 + r];
        if (x < fminf(tau, Lv[0]))
          insert32(Lv, Li, x, n0 + c);
      }
    }
  }

  uint2* mbuf = (uint2*)smraw;
  const int rowg = b * S_ + s0;
  for (int pass = 0; pass < 2; ++pass) {
    __syncthreads();
    const int rb = pass * 32;
    if (r >= rb && r < rb + 32) {
      #pragma unroll
      for (int i = 0; i < 32; ++i)
        mbuf[(r - rb)*130 + q*32 + (31 - i)] =
            make_uint2(__float_as_uint(Lv[i]), (unsigned)Li[i]);
    }
    __syncthreads();
    if (t < 32) {
      const uint2* Lrow = mbuf + t*130;
      uint2* dst = pw + ((size_t)(rowg + rb + t) * SPLIT_ + split) * 32;
      int p0 = 0, p1 = 0, p2 = 0, p3 = 0;
      for (int k = 0; k < 32; ++k) {
        float bv = 3.0e38f; unsigned bi = 0xFFFFFFFFu; int bq = 0;
        int pa[4] = {p0, p1, p2, p3};
        #pragma unroll
        for (int q4 = 0; q4 < 4; ++q4) {
          if (pa[q4] < 32) {
            uint2 e = Lrow[q4*32 + pa[q4]];
            float v = __uint_as_float(e.x);
            if (v < bv || (v == bv && e.y < bi)) { bv = v; bi = e.y; bq = q4; }
          }
        }
        dst[k] = make_uint2(__float_as_uint(bv), bi);
        if (bq == 0) p0++; else if (bq == 1) p1++; else if (bq == 2) p2++; else p3++;
      }
    }
  }
}

// =====================================================================
// K3: MFMA MLP (bf16 2-split) + fused bias/relu/maxpool.
// r13: k_sel FUSED here as a parallel rank-select prelude.  Each of the
// 128 entries of the row's 4 sorted-ascending 32-lists computes its
// global rank (own pos + lower_bound in the other 3 lists, exact
// (v,idx)-lex comparator == k_sel's tie-break; (v,idx) pairs distinct
// since splits partition candidates); rank<32 scatters into nIx[rank].
// Same SET as k_sel's output; order irrelevant (maxpool over k).
// =====================================================================
__device__ __forceinline__ void layer_mfma(
    int lane, int wv, const float* Xf, float* Hf,
    const float* __restrict__ wgt, const float* scl, const float* bia)
{
  const int quad = lane >> 4, mcol = lane & 15;
  const int o = wv*16 + mcol;                 // this wave's output column
  const float sc = scl[o];
  short8_ B0[2], B1[2];
  #pragma unroll
  for (int kt = 0; kt < 2; ++kt) {
    const float* wp = wgt + o*64 + kt*32 + quad*8;
    float4 u0 = *(const float4*)(wp);
    float4 u1 = *(const float4*)(wp + 4);
    float f[8] = {u0.x*sc,u0.y*sc,u0.z*sc,u0.w*sc,
                  u1.x*sc,u1.y*sc,u1.z*sc,u1.w*sc};
    bf2split8(f, B0[kt], B1[kt]);
  }
  const float bo = bia[o];
  const int kt2 = (o >> 5) & 1, qk2 = (o >> 3) & 3, h2 = (o >> 2) & 1, j2 = o & 3;
  #pragma unroll
  for (int mt = 0; mt < 2; ++mt) {
    short8_ A0[2], A1[2];
    #pragma unroll
    for (int kt = 0; kt < 2; ++kt) {
      float4 x0 = *(const float4*)(Xf + (((mt*2+kt)*2+0)*256) + lane*4);
      float4 x1 = *(const float4*)(Xf + (((mt*2+kt)*2+1)*256) + lane*4);
      float f[8] = {x0.x,x0.y,x0.z,x0.w, x1.x,x1.y,x1.z,x1.w};
      bf2split8(f, A0[kt], A1[kt]);
    }
    f32x4_ a = {0.f, 0.f, 0.f, 0.f};
    #pragma unroll
    for (int kt = 0; kt < 2; ++kt) {
      a = __builtin_amdgcn_mfma_f32_16x16x32_bf16(A0[kt], B0[kt], a, 0,0,0);
      a = __builtin_amdgcn_mfma_f32_16x16x32_bf16(A0[kt], B1[kt], a, 0,0,0);
      a = __builtin_amdgcn_mfma_f32_16x16x32_bf16(A1[kt], B0[kt], a, 0,0,0);
    }
    #pragma unroll
    for (int reg = 0; reg < 4; ++reg) {
      int ml = quad*4 + reg;                  // m within mtile
      float hval = fmaxf(a[reg] + bo, 0.f);
      Hf[((mt*2 + kt2)*2 + h2)*256 + (qk2*16 + ml)*4 + j2] = hval;
    }
  }
}

__global__ __launch_bounds__(256) void k_mlp(
    const float* __restrict__ points, const uint2* __restrict__ pw,
    const float* __restrict__ w0, const float* __restrict__ b0,
    const float* __restrict__ g0, const float* __restrict__ be0,
    const float* __restrict__ m0, const float* __restrict__ v0,
    const float* __restrict__ w1, const float* __restrict__ b1,
    const float* __restrict__ g1, const float* __restrict__ be1,
    const float* __restrict__ m1, const float* __restrict__ v1,
    const float* __restrict__ w2, const float* __restrict__ b2,
    const float* __restrict__ g2, const float* __restrict__ be2,
    const float* __restrict__ m2, const float* __restrict__ v2,
    float* __restrict__ out)
{
  __shared__ __align__(16) float Xf[2048];   // 8 segs x 1KB
  __shared__ __align__(16) float Hf[2048];
  __shared__ float scl[128];
  __shared__ float bia[128];
  __shared__ int   nIx[32];
  __shared__ __align__(8) uint2 Lr[128];     // row's 4 sorted 32-lists

  const int t  = threadIdx.x;
  const int bs = blockIdx.x;
  const int b  = bs >> 11;
  const int lane = t & 63, wv = t >> 6;
  const int quad = lane >> 4, mcol = lane & 15;

  // ---- fused k_sel prelude: load lists + layer-0 BN fold in parallel ----
  if (t < 128) Lr[t] = pw[(size_t)bs * (SPLIT_*32) + t];
  if (t >= 128) {                            // layer-0 BN fold, threads 128..255
    int i = t - 128;
    float sc = g0[i] * rsqrtf(v0[i] + 1e-5f);
    scl[i] = sc;
    bia[i] = (b0[i] - m0[i]) * sc + be0[i];
  }
  __syncthreads();
  if (t < 128) {
    uint2 e = Lr[t];
    float ev = __uint_as_float(e.x);
    int rank = t & 31;                       // own position in own list
    #pragma unroll
    for (int oq = 1; oq < 4; ++oq) {
      const uint2* L = Lr + ((((t >> 5) + oq) & 3) << 5);
      int lo = 0;
      #pragma unroll
      for (int stp = 16; stp > 0; stp >>= 1) {
        uint2 c = L[lo + stp - 1];
        float cv = __uint_as_float(c.x);
        bool lt = (cv < ev) || (cv == ev && c.y < e.y);
        lo += lt ? stp : 0;
      }
      { // final correction: count may be up to 32
        uint2 c = L[lo];
        float cv = __uint_as_float(c.x);
        bool lt = (cv < ev) || (cv == ev && c.y < e.y);
        lo += lt ? 1 : 0;
      }
      rank += lo;
    }
    if (rank < 32) nIx[rank] = (int)e.y;
  }
  __syncthreads();
  // stage X (32 rows x 64 ch fp32) into fragment-major segments
  #pragma unroll
  for (int rep = 0; rep < 2; ++rep) {
    int task = rep*256 + t;
    int row = task >> 4, j4 = task & 15;
    float4 v = *(const float4*)(points + ((size_t)b*N_ + nIx[row])*64 + j4*4);
    int kt = j4 >> 3, qk = (j4 >> 1) & 3, h = j4 & 1;
    *(float4*)(Xf + (((row>>4)*2 + kt)*2 + h)*256 + (qk*16 + (row&15))*4) = v;
  }
  __syncthreads();

  layer_mfma(lane, wv, Xf, Hf, w0, scl, bia);      // X -> H
  __syncthreads();
  if (t < 64) {
    float sc = g1[t] * rsqrtf(v1[t] + 1e-5f);
    scl[t] = sc;
    bia[t] = (b1[t] - m1[t]) * sc + be1[t];
  }
  __syncthreads();
  layer_mfma(lane, wv, Hf, Xf, w1, scl, bia);      // H -> X
  __syncthreads();
  if (t < 128) {
    float sc = g2[t] * rsqrtf(v2[t] + 1e-5f);
    scl[t] = sc;
    bia[t] = (b2[t] - m2[t]) * sc + be2[t];
  }
  __syncthreads();

  // ---- layer 2: 64 -> 128, fused maxpool.  A-frags hoisted ----
  short8_ A0[2][2], A1[2][2];
  #pragma unroll
  for (int mt = 0; mt < 2; ++mt)
    #pragma unroll
    for (int kt = 0; kt < 2; ++kt) {
      float4 x0 = *(const float4*)(Xf + (((mt*2+kt)*2+0)*256) + lane*4);
      float4 x1 = *(const float4*)(Xf + (((mt*2+kt)*2+1)*256) + lane*4);
      float f[8] = {x0.x,x0.y,x0.z,x0.w, x1.x,x1.y,x1.z,x1.w};
      bf2split8(f, A0[mt][kt], A1[mt][kt]);
    }
  float* outp = out + (size_t)(B_*S_)*3 + (size_t)bs*128;
  #pragma unroll
  for (int sub = 0; sub < 2; ++sub) {
    const int o = (wv*2 + sub)*16 + mcol;
    const float sc = scl[o];
    short8_ B0[2], B1[2];
    #pragma unroll
    for (int kt = 0; kt < 2; ++kt) {
      const float* wp = w2 + o*64 + kt*32 + quad*8;
      float4 u0 = *(const float4*)(wp);
      float4 u1 = *(const float4*)(wp + 4);
      float f[8] = {u0.x*sc,u0.y*sc,u0.z*sc,u0.w*sc,
                    u1.x*sc,u1.y*sc,u1.z*sc,u1.w*sc};
      bf2split8(f, B0[kt], B1[kt]);
    }
    float vmax = -3.0e38f;
    #pragma unroll
    for (int mt = 0; mt < 2; ++mt) {
      f32x4_ a = {0.f, 0.f, 0.f, 0.f};
      #pragma unroll
      for (int kt = 0; kt < 2; ++kt) {
        a = __builtin_amdgcn_mfma_f32_16x16x32_bf16(A0[mt][kt], B0[kt], a, 0,0,0);
        a = __builtin_amdgcn_mfma_f32_16x16x32_bf16(A0[mt][kt], B1[kt], a, 0,0,0);
        a = __builtin_amdgcn_mfma_f32_16x16x32_bf16(A1[mt][kt], B0[kt], a, 0,0,0);
      }
      vmax = fmaxf(vmax, fmaxf(fmaxf(a[0], a[1]), fmaxf(a[2], a[3])));
    }
    vmax = fmaxf(vmax, __shfl_xor(vmax, 16));
    vmax = fmaxf(vmax, __shfl_xor(vmax, 32));
    if (quad == 0) outp[o] = fmaxf(vmax + bia[o], 0.f);
  }
}

// =====================================================================
extern "C" void kernel_launch(void* const* d_in, const int* in_sizes, int n_in,
                              void* d_out, int out_size, void* d_ws, size_t ws_size,
                              hipStream_t stream)
{
  const float* xyz  = (const float*)d_in[0];
  const float* pts  = (const float*)d_in[1];
  const int*   sidx = (const int*)  d_in[2];
  const float* w0 = (const float*)d_in[3];
  const float* b0 = (const float*)d_in[4];
  const float* g0 = (const float*)d_in[5];
  const float* be0= (const float*)d_in[6];
  const float* m0 = (const float*)d_in[7];
  const float* v0 = (const float*)d_in[8];
  const float* w1 = (const float*)d_in[9];
  const float* b1 = (const float*)d_in[10];
  const float* g1 = (const float*)d_in[11];
  const float* be1= (const float*)d_in[12];
  const float* m1 = (const float*)d_in[13];
  const float* v1 = (const float*)d_in[14];
  const float* w2 = (const float*)d_in[15];
  const float* b2 = (const float*)d_in[16];
  const float* g2 = (const float*)d_in[17];
  const float* be2= (const float*)d_in[18];
  const float* m2 = (const float*)d_in[19];
  const float* v2 = (const float*)d_in[20];

  float* out = (float*)d_out;
  // ws: sqn (512KB) | nbr (2MB, reserved) | pw (16.8MB) | planes (3 x 16.78MB)
  float* sqn = (float*)d_ws;
  uint2* pw  = (uint2*)((char*)d_ws + (size_t)B_*N_*4 + (size_t)B_*S_*K_*4);
  char*  pl  = (char*)d_ws + (size_t)B_*N_*4 + (size_t)B_*S_*K_*4
             + (size_t)B_*S_*SPLIT_*32*8;
  short* P0 = (short*)pl;
  short* P1 = P0 + PLANE_;
  short* P2 = P1 + PLANE_;
  const size_t need = (size_t)B_*N_*4 + (size_t)B_*S_*K_*4
                    + (size_t)B_*S_*SPLIT_*32*8 + 3*PLANE_*2;

  if (ws_size >= need) {
    k_prep<<<(B_*N_)/256, 256, 0, stream>>>(xyz, pts, sidx, out, sqn, P0, P1, P2);
    k_knn <<<B_*32*SPLIT_, 256, 0, stream>>>(P0, P1, P2, sidx, sqn, pw);
  } else {
    k_prep_fb<<<(B_*N_)/256, 256, 0, stream>>>(xyz, pts, sidx, out, sqn);
    k_knn_fb <<<B_*32*SPLIT_, 256, 0, stream>>>(pts, sidx, sqn, pw);
  }
  k_mlp <<<B_*S_, 256, 0, stream>>>(pts, pw,
            w0,b0,g0,be0,m0,v0, w1,b1,g1,be1,m1,v1, w2,b2,g2,be2,m2,v2, out);
}

// Round 4
// 759.336 us; speedup vs baseline: 1.2249x; 1.0433x over previous
//
#include <hip/hip_runtime.h>

#define B_  8
#define N_  16384
#define D_  64
#define S_  2048
#define K_  32
#define SPLIT_  4
#define NSPL_   (N_/SPLIT_)       // 4096 candidates per block
#define CH32_   (NSPL_/32)        // 128 chunks of 32
#define PLANE_  ((size_t)B_*N_*64) // shorts per plane (8.39M = 16.78 MB)

using short8_ = __attribute__((ext_vector_type(8))) short;
using f32x4_  = __attribute__((ext_vector_type(4))) float;

// =====================================================================
// exact bf16 triple-split of fp32 (truncation-based): f = h0 + h1 + h2
// =====================================================================
__device__ __forceinline__ void bf3split(float f, short& h0, short& h1, short& h2)
{
  unsigned u0 = __float_as_uint(f);
  float f0 = __uint_as_float(u0 & 0xFFFF0000u);
  h0 = (short)(u0 >> 16);
  float r1 = f - f0;
  unsigned u1 = __float_as_uint(r1);
  float f1 = __uint_as_float(u1 & 0xFFFF0000u);
  h1 = (short)(u1 >> 16);
  float r2 = r1 - f1;                 // <= 8 significant bits: bf16-exact
  h2 = (short)(__float_as_uint(r2) >> 16);
}

// bf16 2-split of 8 floats (for the MLP; residual ~2^-16 rel)
__device__ __forceinline__ void bf2split8(const float* f, short8_& h0, short8_& h1)
{
  #pragma unroll
  for (int j = 0; j < 8; ++j) {
    unsigned u = __float_as_uint(f[j]);
    h0[j] = (short)(u >> 16);
    float r = f[j] - __uint_as_float(u & 0xFFFF0000u);
    h1[j] = (short)(__float_as_uint(r) >> 16);
  }
}

// sorted-DESCENDING 32-entry list (Lv[0] = largest kept)
__device__ __forceinline__ void insert32(float (&Lv)[32], int (&Li)[32], float x, int n)
{
  bool ci = x < Lv[0];
  #pragma unroll
  for (int i = 0; i < 31; ++i) {
    bool c1 = x < Lv[i+1];
    float nv = c1 ? Lv[i+1] : (ci ? x : Lv[i]);
    int   ni = c1 ? Li[i+1] : (ci ? n : Li[i]);
    Lv[i] = nv; Li[i] = ni;
    ci = c1;
  }
  Lv[31] = ci ? x : Lv[31];
  Li[31] = ci ? n : Li[31];
}

// =====================================================================
// K1 (fast path): sqn + new_xyz gather + fragment-major bf16x3 planes
// sqn: EXACT round-3 expression (bit-identical keys -> selection).
// =====================================================================
__global__ __launch_bounds__(256) void k_prep(
    const float* __restrict__ xyz, const float* __restrict__ points,
    const int* __restrict__ sidx, float* __restrict__ out, float* __restrict__ sqn,
    short* __restrict__ P0, short* __restrict__ P1, short* __restrict__ P2)
{
  int tid = blockIdx.x * 256 + threadIdx.x;      // 0 .. B*N-1
  const float4* p = (const float4*)(points + (size_t)tid * 64);

  float s = 0.f;
  #pragma unroll
  for (int i = 0; i < 16; ++i) {
    float4 v = p[i];
    s += v.x*v.x + v.y*v.y + v.z*v.z + v.w*v.w;
  }
  sqn[tid] = s;

  int n = tid & (N_-1);
  int c = n >> 6, ct = (n >> 4) & 3, mc = n & 15;
  size_t segbase = (((size_t)(tid >> 14) * 256 + c) * 4 + ct) * 2;  // *512 shorts

  #pragma unroll
  for (int g = 0; g < 8; ++g) {                  // (kt=g>>2, qd=g&3), dims 8g..8g+7
    float4 a = p[2*g], b4 = p[2*g+1];
    float f[8] = {a.x,a.y,a.z,a.w, b4.x,b4.y,b4.z,b4.w};
    short8_ h0v, h1v, h2v;
    #pragma unroll
    for (int j = 0; j < 8; ++j) {
      short h0, h1, h2;
      bf3split(f[j], h0, h1, h2);
      h0v[j] = h0; h1v[j] = h1; h2v[j] = h2;
    }
    size_t off = ((segbase + (g>>2))*64 + (size_t)(g&3)*16 + mc)*8;
    *(short8_*)(P0 + off) = h0v;
    *(short8_*)(P1 + off) = h1v;
    *(short8_*)(P2 + off) = h2v;
  }
  if (tid < B_*S_) {
    int b = tid >> 11, ss = tid & (S_-1);
    int nn = sidx[ss];
    const float* src = xyz + ((size_t)b * N_ + nn) * 3;
    out[(size_t)tid*3+0] = src[0];
    out[(size_t)tid*3+1] = src[1];
    out[(size_t)tid*3+2] = src[2];
  }
}

// =====================================================================
// K2 (fast path), r14: r11 steady-state + peeled fill prologue.
//  - chunks 0-3: keys written DIRECTLY into Lv/Li (no FIFO, no
//    thresholds; identical admitted set -- r11 admitted all of them
//    through the sentinel thresholds anyway, via ~28 insert32 drains)
//  - at chunk 4: one in-register bitonic sort, (v,idx)-lex descending
//    == the unique order insert32 produces (all (v,idx) distinct)
//  - steady threshold: thr = min(t24, ownL0).  tmin dropped: superset
//    proof needs each bound >= row-32nd-final; t24 & ownL0 each qualify.
//  - steady per-chunk body otherwise VERBATIM r11.
// =====================================================================
__global__ __launch_bounds__(256) void k_knn(
    const short* __restrict__ P0, const short* __restrict__ P1,
    const short* __restrict__ P2, const int* __restrict__ sidx,
    const float* __restrict__ sqn, uint2* __restrict__ pw)
{
  // LDS: Dtr [64r][36c] 9216 | qbuf 16384 @9216 (total 25600)
  // merge phase aliases front as uint2 mbuf[32][130] = 33280 (all dead then)
  __shared__ __align__(16) char smraw[33280];
  float* Dtr = (float*)smraw;
  uint2* qb  = (uint2*)(smraw + 9216);   // [8 slots][256 lanes]

  const int t = threadIdx.x;
  const int b     = blockIdx.x & 7;          // XCD swizzle
  const int y     = blockIdx.x >> 3;
  const int tile  = y & 31;
  const int split = y >> 5;
  const int s0 = tile * 64;
  const float* Qb = sqn + (size_t)b * N_;

  const int lane = t & 63, wv = t >> 6;
  const int quad = lane >> 4, mcol = lane & 15;

  // ---- A fragments (wave wv owns sampled rows 16*wv..+15), from planes ----
  short8_ A0[2], A1[2], A2[2];
  {
    int srow = sidx[s0 + 16*wv + mcol];
    int cs = srow >> 6, cts = (srow >> 4) & 3, ms = srow & 15;
    size_t ab = (((size_t)(b*256 + cs))*4 + cts)*2*512 + ((size_t)quad*16 + ms)*8;
    #pragma unroll
    for (int kt = 0; kt < 2; ++kt) {
      A0[kt] = *(const short8_*)(P0 + ab + kt*512);
      A1[kt] = *(const short8_*)(P1 + ab + kt*512);
      A2[kt] = *(const short8_*)(P2 + ab + kt*512);
    }
  }

  float Lv[32]; int Li[32];
  #pragma unroll
  for (int i = 0; i < 32; ++i) { Lv[i] = 3.0e38f; Li[i] = 0; }

  const int r = t >> 2;        // selection row 0..63
  const int q = t & 3;         // stream within row
  const int n0base = split * NSPL_;
  const size_t bc8base = (size_t)b * 256;

  int qhead = 0, qtail = 0;    // per-lane FIFO state

  // selection pass for the chunk whose keys sit in Dtr (wave-private rows)
  auto do_select = [&](int n0sel) {
    // ---- adaptive drain: pass only when some lane has >=2 pending ----
    if (__any((qtail - qhead) >= 2)) {
      if (qhead < qtail) {
        uint2 e = qb[(qhead & 7)*256 + t];
        qhead++;
        float x = __uint_as_float(e.x);
        if (x < Lv[0])
          insert32(Lv, Li, x, (int)e.y);
      }
    }
    // ---- admission: exact bounds (t24 + own 32nd), cheap FIFO pushes ----
    float ownL0 = Lv[0];
    float t24 = Lv[24];                       // stream 8th-smallest
    t24 = fmaxf(t24, __shfl_xor(t24, 1));
    t24 = fmaxf(t24, __shfl_xor(t24, 2));     // max over streams: row-32nd <= t24
    const float thr = fminf(t24, ownL0);

    float4 ka = *(const float4*)(Dtr + r*36 + q*8);
    float4 kb = *(const float4*)(Dtr + r*36 + q*8 + 4);
    float x8[8] = {ka.x,ka.y,ka.z,ka.w, kb.x,kb.y,kb.z,kb.w};
    unsigned m = 0;
    #pragma unroll
    for (int i = 0; i < 8; ++i)
      m |= (x8[i] < thr) ? (1u << i) : 0u;
    while (m) {                               // per-lane, cheap body
      int i = __ffs(m) - 1;
      m &= m - 1;
      float xlo = (i & 1) ? ((i & 2) ? x8[3] : x8[1]) : ((i & 2) ? x8[2] : x8[0]);
      float xhi = (i & 1) ? ((i & 2) ? x8[7] : x8[5]) : ((i & 2) ? x8[6] : x8[4]);
      float x = (i & 4) ? xhi : xlo;
      if (qtail - qhead >= 8) {               // full: drain one in-place (rare)
        uint2 e = qb[(qhead & 7)*256 + t];
        qhead++;
        float xe = __uint_as_float(e.x);
        if (xe < Lv[0])
          insert32(Lv, Li, xe, (int)e.y);
      }
      qb[(qtail & 7)*256 + t] = make_uint2(__float_as_uint(x), (unsigned)(n0sel + q*8 + i));
      qtail++;
    }
  };

  // running plane offset for chunk 0 (n0base % 64 == 0)
  size_t goff = ((bc8base + (size_t)(n0base >> 6)) * 8) * 512 + (size_t)lane * 8;

  short8_ b0[2][2], b1[2][2], b2[2][2];   // [ct][kt]
  float sq0, sq1;

  auto kload = [&](int n0c) {
    #pragma unroll
    for (int s = 0; s < 4; ++s) {           // s = ct*2 + kt
      b0[s>>1][s&1] = *(const short8_*)(P0 + goff + (size_t)s*512);
      b1[s>>1][s&1] = *(const short8_*)(P1 + goff + (size_t)s*512);
      b2[s>>1][s&1] = *(const short8_*)(P2 + goff + (size_t)s*512);
    }
    sq0 = Qb[n0c + mcol];                   // ct=0 column sqnorm
    sq1 = Qb[n0c + 16 + mcol];              // ct=1 column sqnorm
    goff += 2048;                           // 4 slots x 512 shorts per chunk
  };

  auto kmfma = [&]() {
    #pragma unroll
    for (int ct = 0; ct < 2; ++ct) {
      f32x4_ a = {0.f, 0.f, 0.f, 0.f};
      #pragma unroll
      for (int kt = 0; kt < 2; ++kt) {
        a = __builtin_amdgcn_mfma_f32_16x16x32_bf16(A0[kt], b0[ct][kt], a, 0,0,0);
        a = __builtin_amdgcn_mfma_f32_16x16x32_bf16(A0[kt], b1[ct][kt], a, 0,0,0);
        a = __builtin_amdgcn_mfma_f32_16x16x32_bf16(A1[kt], b0[ct][kt], a, 0,0,0);
        a = __builtin_amdgcn_mfma_f32_16x16x32_bf16(A1[kt], b1[ct][kt], a, 0,0,0);
        a = __builtin_amdgcn_mfma_f32_16x16x32_bf16(A0[kt], b2[ct][kt], a, 0,0,0);
        a = __builtin_amdgcn_mfma_f32_16x16x32_bf16(A2[kt], b0[ct][kt], a, 0,0,0);
        a = __builtin_amdgcn_mfma_f32_16x16x32_bf16(A1[kt], b2[ct][kt], a, 0,0,0);
        a = __builtin_amdgcn_mfma_f32_16x16x32_bf16(A2[kt], b1[ct][kt], a, 0,0,0);
      }
      // keys -> Dtr (wave-local rows). C/D: col=lane&15, row=quad*4+reg
      int cc = 16*ct + mcol;
      float sq = ct ? sq1 : sq0;
      int rb = 16*wv + 4*quad;
      Dtr[(rb+0)*36 + cc] = sq - 2.f*a[0];
      Dtr[(rb+1)*36 + cc] = sq - 2.f*a[1];
      Dtr[(rb+2)*36 + cc] = sq - 2.f*a[2];
      Dtr[(rb+3)*36 + cc] = sq - 2.f*a[3];
    }
    // no barrier anywhere: Dtr rows 16wv..16wv+15 are wave-private (lgkmcnt)
  };

  // direct fill of list slots 8J..8J+7 from Dtr (chunk J's keys); static J
  #define FILLJ(J) { \
    float4 ka = *(const float4*)(Dtr + r*36 + q*8); \
    float4 kb = *(const float4*)(Dtr + r*36 + q*8 + 4); \
    float x8f[8] = {ka.x,ka.y,ka.z,ka.w, kb.x,kb.y,kb.z,kb.w}; \
    _Pragma("unroll") \
    for (int i = 0; i < 8; ++i) { \
      Lv[(J)*8 + i] = x8f[i]; \
      Li[(J)*8 + i] = n0base + (J)*32 + q*8 + i; } }

  // ---- prologue: chunks 0-4; fills for 0-3, one sort, then steady ----
  kload(n0base + 0*32);            kmfma();
  kload(n0base + 1*32); FILLJ(0);  kmfma();
  kload(n0base + 2*32); FILLJ(1);  kmfma();
  kload(n0base + 3*32); FILLJ(2);  kmfma();
  kload(n0base + 4*32); FILLJ(3);
  // bitonic sort, (v,idx)-lex DESCENDING (pos 0 = greatest) == insert32 order
  #pragma unroll
  for (int k = 2; k <= 32; k <<= 1) {
    #pragma unroll
    for (int j2 = k >> 1; j2 > 0; j2 >>= 1) {
      #pragma unroll
      for (int i = 0; i < 32; ++i) {
        int l = i ^ j2;
        if (l > i) {
          bool g = (Lv[l] > Lv[i]) || (Lv[l] == Lv[i] && Li[l] > Li[i]);
          bool sw = ((i & k) == 0) ? g : !g;
          float tv = sw ? Lv[l] : Lv[i];
          float uv = sw ? Lv[i] : Lv[l];
          int   ti = sw ? Li[l] : Li[i];
          int   ui = sw ? Li[i] : Li[l];
          Lv[i] = tv; Lv[l] = uv; Li[i] = ti; Li[l] = ui;
        }
      }
    }
  }
  kmfma();

  // ---- steady loop: verbatim r11 body ----
  for (int ch = 5; ch < CH32_; ++ch) {
    kload(n0base + ch*32);
    do_select(n0base + ch*32 - 32);
    kmfma();
  }
  do_select(n0base + NSPL_ - 32);           // selection for the last chunk

  // ---- final drain ----
  while (__any(qhead < qtail)) {
    if (qhead < qtail) {
      uint2 e = qb[(qhead & 7)*256 + t];
      qhead++;
      float x = __uint_as_float(e.x);
      if (x < Lv[0])
        insert32(Lv, Li, x, (int)e.y);
    }
  }

  // ---- in-block 4-pointer merge (streams stored reversed -> ascending) ----
  uint2* mbuf = (uint2*)smraw;                 // [32][130]
  const int rowg = b * S_ + s0;
  for (int pass = 0; pass < 2; ++pass) {
    __syncthreads();
    const int rb = pass * 32;
    if (r >= rb && r < rb + 32) {
      #pragma unroll
      for (int i = 0; i < 32; ++i)
        mbuf[(r - rb)*130 + q*32 + (31 - i)] =
            make_uint2(__float_as_uint(Lv[i]), (unsigned)Li[i]);
    }
    __syncthreads();
    if (t < 32) {
      const uint2* Lrow = mbuf + t*130;
      uint2* dst = pw + ((size_t)(rowg + rb + t) * SPLIT_ + split) * 32;
      int p0 = 0, p1 = 0, p2 = 0, p3 = 0;
      for (int k = 0; k < 32; ++k) {
        float bv = 3.0e38f; unsigned bi = 0xFFFFFFFFu; int bq = 0;
        int pa[4] = {p0, p1, p2, p3};
        #pragma unroll
        for (int q4 = 0; q4 < 4; ++q4) {
          if (pa[q4] < 32) {
            uint2 e = Lrow[q4*32 + pa[q4]];
            float v = __uint_as_float(e.x);
            if (v < bv || (v == bv && e.y < bi)) { bv = v; bi = e.y; bq = q4; }
          }
        }
        dst[k] = make_uint2(__float_as_uint(bv), bi);
        if (bq == 0) p0++; else if (bq == 1) p1++; else if (bq == 2) p2++; else p3++;
      }
    }
  }
  #undef FILLJ
}

// =====================================================================
// FALLBACK path (ws too small): round-3 kernels, proven correct
// =====================================================================
__global__ __launch_bounds__(256) void k_prep_fb(
    const float* __restrict__ xyz, const float* __restrict__ points,
    const int* __restrict__ sidx, float* __restrict__ out, float* __restrict__ sqn)
{
  int tid = blockIdx.x * 256 + threadIdx.x;
  const float4* p = (const float4*)(points + (size_t)tid * 64);
  float s = 0.f;
  #pragma unroll
  for (int i = 0; i < 16; ++i) {
    float4 v = p[i];
    s += v.x*v.x + v.y*v.y + v.z*v.z + v.w*v.w;
  }
  sqn[tid] = s;
  if (tid < B_*S_) {
    int b = tid >> 11, ss = tid & (S_-1);
    int n = sidx[ss];
    const float* src = xyz + ((size_t)b * N_ + n) * 3;
    out[(size_t)tid*3+0] = src[0];
    out[(size_t)tid*3+1] = src[1];
    out[(size_t)tid*3+2] = src[2];
  }
}

__global__ __launch_bounds__(256) void k_knn_fb(
    const float* __restrict__ points, const int* __restrict__ sidx,
    const float* __restrict__ sqn, uint2* __restrict__ pw)
{
  __shared__ __align__(16) char smraw[45312];
  short* Bp0 = (short*)smraw;
  short* Bp1 = (short*)(smraw + 9216);
  short* Bp2 = (short*)(smraw + 18432);
  float* Dt  = (float*)(smraw + 27648);
  float* sqc = (float*)(smraw + 45056);

  const int t = threadIdx.x;
  const int b     = blockIdx.x & 7;
  const int y     = blockIdx.x >> 3;
  const int tile  = y & 31;
  const int split = y >> 5;
  const int s0 = tile * 64;
  const float* Pb = points + (size_t)b * N_ * 64;
  const float* Qb = sqn    + (size_t)b * N_;

  const int lane = t & 63, wv = t >> 6;
  const int quad = lane >> 4, mcol = lane & 15;

  short8_ A0[2], A1[2], A2[2];
  {
    int srow = sidx[s0 + 16*wv + mcol];
    const float* ar = Pb + (size_t)srow * 64;
    #pragma unroll
    for (int kt = 0; kt < 2; ++kt) {
      float4 v0 = *(const float4*)(ar + 32*kt + 8*quad);
      float4 v1 = *(const float4*)(ar + 32*kt + 8*quad + 4);
      float f[8] = {v0.x,v0.y,v0.z,v0.w,v1.x,v1.y,v1.z,v1.w};
      #pragma unroll
      for (int j = 0; j < 8; ++j) {
        short h0, h1, h2;
        bf3split(f[j], h0, h1, h2);
        A0[kt][j] = h0; A1[kt][j] = h1; A2[kt][j] = h2;
      }
    }
  }

  float Lv[32]; int Li[32];
  #pragma unroll
  for (int i = 0; i < 32; ++i) { Lv[i] = 3.0e38f; Li[i] = 0; }

  const int r = t >> 2;
  const int q = t & 3;
  const int n0base = split * NSPL_;

  for (int ch = 0; ch < NSPL_/64; ++ch) {
    const int n0 = n0base + ch * 64;
    {
      const int n = t & 63, jg = t >> 6;
      const float* src = Pb + (size_t)(n0 + n) * 64 + 16*jg;
      float4 u0 = *(const float4*)(src);
      float4 u1 = *(const float4*)(src + 4);
      float4 u2 = *(const float4*)(src + 8);
      float4 u3 = *(const float4*)(src + 12);
      float f[16] = {u0.x,u0.y,u0.z,u0.w, u1.x,u1.y,u1.z,u1.w,
                     u2.x,u2.y,u2.z,u2.w, u3.x,u3.y,u3.z,u3.w};
      short8_ p0[2], p1[2], p2[2];
      #pragma unroll
      for (int j = 0; j < 16; ++j) {
        short h0, h1, h2;
        bf3split(f[j], h0, h1, h2);
        p0[j>>3][j&7] = h0; p1[j>>3][j&7] = h1; p2[j>>3][j&7] = h2;
      }
      *(short8_*)(Bp0 + n*72 + 16*jg)     = p0[0];
      *(short8_*)(Bp0 + n*72 + 16*jg + 8) = p0[1];
      *(short8_*)(Bp1 + n*72 + 16*jg)     = p1[0];
      *(short8_*)(Bp1 + n*72 + 16*jg + 8) = p1[1];
      *(short8_*)(Bp2 + n*72 + 16*jg)     = p2[0];
      *(short8_*)(Bp2 + n*72 + 16*jg + 8) = p2[1];
      if (t < 16) *(float4*)(sqc + 4*t) = *(const float4*)(Qb + n0 + 4*t);
    }
    __syncthreads();

    f32x4_ acc[4];
    #pragma unroll
    for (int ct = 0; ct < 4; ++ct) {
      const int boff = (16*ct + mcol)*72 + 8*quad;
      short8_ b0[2], b1[2], b2[2];
      b0[0] = *(const short8_*)(Bp0 + boff); b0[1] = *(const short8_*)(Bp0 + boff + 32);
      b1[0] = *(const short8_*)(Bp1 + boff); b1[1] = *(const short8_*)(Bp1 + boff + 32);
      b2[0] = *(const short8_*)(Bp2 + boff); b2[1] = *(const short8_*)(Bp2 + boff + 32);
      f32x4_ a = {0.f, 0.f, 0.f, 0.f};
      #pragma unroll
      for (int kt = 0; kt < 2; ++kt) {
        a = __builtin_amdgcn_mfma_f32_16x16x32_bf16(A0[kt], b0[kt], a, 0,0,0);
        a = __builtin_amdgcn_mfma_f32_16x16x32_bf16(A0[kt], b1[kt], a, 0,0,0);
        a = __builtin_amdgcn_mfma_f32_16x16x32_bf16(A1[kt], b0[kt], a, 0,0,0);
        a = __builtin_amdgcn_mfma_f32_16x16x32_bf16(A1[kt], b1[kt], a, 0,0,0);
        a = __builtin_amdgcn_mfma_f32_16x16x32_bf16(A0[kt], b2[kt], a, 0,0,0);
        a = __builtin_amdgcn_mfma_f32_16x16x32_bf16(A2[kt], b0[kt], a, 0,0,0);
        a = __builtin_amdgcn_mfma_f32_16x16x32_bf16(A1[kt], b2[kt], a, 0,0,0);
        a = __builtin_amdgcn_mfma_f32_16x16x32_bf16(A2[kt], b1[kt], a, 0,0,0);
      }
      acc[ct] = a;
    }
    #pragma unroll
    for (int ct = 0; ct < 4; ++ct) {
      int c = 16*ct + mcol;
      float sq = sqc[c];
      float4 kv;
      kv.x = sq - 2.f*acc[ct][0];
      kv.y = sq - 2.f*acc[ct][1];
      kv.z = sq - 2.f*acc[ct][2];
      kv.w = sq - 2.f*acc[ct][3];
      *(float4*)(Dt + c*68 + 16*wv + 4*quad) = kv;
    }
    __syncthreads();

    float L0 = Lv[0];
    L0 = fminf(L0, __shfl_xor(L0, 1));
    L0 = fminf(L0, __shfl_xor(L0, 2));
    const float tau = L0;
    #pragma unroll
    for (int g = 0; g < 4; ++g) {
      #pragma unroll
      for (int u = 0; u < 4; ++u) {
        int c = q*16 + g*4 + u;
        float x = Dt[c*68 + r];
        if (x < fminf(tau, Lv[0]))
          insert32(Lv, Li, x, n0 + c);
      }
    }
  }

  uint2* mbuf = (uint2*)smraw;
  const int rowg = b * S_ + s0;
  for (int pass = 0; pass < 2; ++pass) {
    __syncthreads();
    const int rb = pass * 32;
    if (r >= rb && r < rb + 32) {
      #pragma unroll
      for (int i = 0; i < 32; ++i)
        mbuf[(r - rb)*130 + q*32 + (31 - i)] =
            make_uint2(__float_as_uint(Lv[i]), (unsigned)Li[i]);
    }
    __syncthreads();
    if (t < 32) {
      const uint2* Lrow = mbuf + t*130;
      uint2* dst = pw + ((size_t)(rowg + rb + t) * SPLIT_ + split) * 32;
      int p0 = 0, p1 = 0, p2 = 0, p3 = 0;
      for (int k = 0; k < 32; ++k) {
        float bv = 3.0e38f; unsigned bi = 0xFFFFFFFFu; int bq = 0;
        int pa[4] = {p0, p1, p2, p3};
        #pragma unroll
        for (int q4 = 0; q4 < 4; ++q4) {
          if (pa[q4] < 32) {
            uint2 e = Lrow[q4*32 + pa[q4]];
            float v = __uint_as_float(e.x);
            if (v < bv || (v == bv && e.y < bi)) { bv = v; bi = e.y; bq = q4; }
          }
        }
        dst[k] = make_uint2(__float_as_uint(bv), bi);
        if (bq == 0) p0++; else if (bq == 1) p1++; else if (bq == 2) p2++; else p3++;
      }
    }
  }
}

// =====================================================================
// K3: MFMA MLP (bf16 2-split) + fused bias/relu/maxpool.
// k_sel fused as parallel rank-select prelude (r13, proven).
// =====================================================================
__device__ __forceinline__ void layer_mfma(
    int lane, int wv, const float* Xf, float* Hf,
    const float* __restrict__ wgt, const float* scl, const float* bia)
{
  const int quad = lane >> 4, mcol = lane & 15;
  const int o = wv*16 + mcol;                 // this wave's output column
  const float sc = scl[o];
  short8_ B0[2], B1[2];
  #pragma unroll
  for (int kt = 0; kt < 2; ++kt) {
    const float* wp = wgt + o*64 + kt*32 + quad*8;
    float4 u0 = *(const float4*)(wp);
    float4 u1 = *(const float4*)(wp + 4);
    float f[8] = {u0.x*sc,u0.y*sc,u0.z*sc,u0.w*sc,
                  u1.x*sc,u1.y*sc,u1.z*sc,u1.w*sc};
    bf2split8(f, B0[kt], B1[kt]);
  }
  const float bo = bia[o];
  const int kt2 = (o >> 5) & 1, qk2 = (o >> 3) & 3, h2 = (o >> 2) & 1, j2 = o & 3;
  #pragma unroll
  for (int mt = 0; mt < 2; ++mt) {
    short8_ A0[2], A1[2];
    #pragma unroll
    for (int kt = 0; kt < 2; ++kt) {
      float4 x0 = *(const float4*)(Xf + (((mt*2+kt)*2+0)*256) + lane*4);
      float4 x1 = *(const float4*)(Xf + (((mt*2+kt)*2+1)*256) + lane*4);
      float f[8] = {x0.x,x0.y,x0.z,x0.w, x1.x,x1.y,x1.z,x1.w};
      bf2split8(f, A0[kt], A1[kt]);
    }
    f32x4_ a = {0.f, 0.f, 0.f, 0.f};
    #pragma unroll
    for (int kt = 0; kt < 2; ++kt) {
      a = __builtin_amdgcn_mfma_f32_16x16x32_bf16(A0[kt], B0[kt], a, 0,0,0);
      a = __builtin_amdgcn_mfma_f32_16x16x32_bf16(A0[kt], B1[kt], a, 0,0,0);
      a = __builtin_amdgcn_mfma_f32_16x16x32_bf16(A1[kt], B0[kt], a, 0,0,0);
    }
    #pragma unroll
    for (int reg = 0; reg < 4; ++reg) {
      int ml = quad*4 + reg;                  // m within mtile
      float hval = fmaxf(a[reg] + bo, 0.f);
      Hf[((mt*2 + kt2)*2 + h2)*256 + (qk2*16 + ml)*4 + j2] = hval;
    }
  }
}

__global__ __launch_bounds__(256) void k_mlp(
    const float* __restrict__ points, const uint2* __restrict__ pw,
    const float* __restrict__ w0, const float* __restrict__ b0,
    const float* __restrict__ g0, const float* __restrict__ be0,
    const float* __restrict__ m0, const float* __restrict__ v0,
    const float* __restrict__ w1, const float* __restrict__ b1,
    const float* __restrict__ g1, const float* __restrict__ be1,
    const float* __restrict__ m1, const float* __restrict__ v1,
    const float* __restrict__ w2, const float* __restrict__ b2,
    const float* __restrict__ g2, const float* __restrict__ be2,
    const float* __restrict__ m2, const float* __restrict__ v2,
    float* __restrict__ out)
{
  __shared__ __align__(16) float Xf[2048];   // 8 segs x 1KB
  __shared__ __align__(16) float Hf[2048];
  __shared__ float scl[128];
  __shared__ float bia[128];
  __shared__ int   nIx[32];
  __shared__ __align__(8) uint2 Lr[128];     // row's 4 sorted 32-lists

  const int t  = threadIdx.x;
  const int bs = blockIdx.x;
  const int b  = bs >> 11;
  const int lane = t & 63, wv = t >> 6;
  const int quad = lane >> 4, mcol = lane & 15;

  // ---- fused k_sel prelude: load lists + layer-0 BN fold in parallel ----
  if (t < 128) Lr[t] = pw[(size_t)bs * (SPLIT_*32) + t];
  if (t >= 128) {                            // layer-0 BN fold, threads 128..255
    int i = t - 128;
    float sc = g0[i] * rsqrtf(v0[i] + 1e-5f);
    scl[i] = sc;
    bia[i] = (b0[i] - m0[i]) * sc + be0[i];
  }
  __syncthreads();
  if (t < 128) {
    uint2 e = Lr[t];
    float ev = __uint_as_float(e.x);
    int rank = t & 31;                       // own position in own list
    #pragma unroll
    for (int oq = 1; oq < 4; ++oq) {
      const uint2* L = Lr + ((((t >> 5) + oq) & 3) << 5);
      int lo = 0;
      #pragma unroll
      for (int stp = 16; stp > 0; stp >>= 1) {
        uint2 c = L[lo + stp - 1];
        float cv = __uint_as_float(c.x);
        bool lt = (cv < ev) || (cv == ev && c.y < e.y);
        lo += lt ? stp : 0;
      }
      { // final correction: count may be up to 32
        uint2 c = L[lo];
        float cv = __uint_as_float(c.x);
        bool lt = (cv < ev) || (cv == ev && c.y < e.y);
        lo += lt ? 1 : 0;
      }
      rank += lo;
    }
    if (rank < 32) nIx[rank] = (int)e.y;
  }
  __syncthreads();
  // stage X (32 rows x 64 ch fp32) into fragment-major segments
  #pragma unroll
  for (int rep = 0; rep < 2; ++rep) {
    int task = rep*256 + t;
    int row = task >> 4, j4 = task & 15;
    float4 v = *(const float4*)(points + ((size_t)b*N_ + nIx[row])*64 + j4*4);
    int kt = j4 >> 3, qk = (j4 >> 1) & 3, h = j4 & 1;
    *(float4*)(Xf + (((row>>4)*2 + kt)*2 + h)*256 + (qk*16 + (row&15))*4) = v;
  }
  __syncthreads();

  layer_mfma(lane, wv, Xf, Hf, w0, scl, bia);      // X -> H
  __syncthreads();
  if (t < 64) {
    float sc = g1[t] * rsqrtf(v1[t] + 1e-5f);
    scl[t] = sc;
    bia[t] = (b1[t] - m1[t]) * sc + be1[t];
  }
  __syncthreads();
  layer_mfma(lane, wv, Hf, Xf, w1, scl, bia);      // H -> X
  __syncthreads();
  if (t < 128) {
    float sc = g2[t] * rsqrtf(v2[t] + 1e-5f);
    scl[t] = sc;
    bia[t] = (b2[t] - m2[t]) * sc + be2[t];
  }
  __syncthreads();

  // ---- layer 2: 64 -> 128, fused maxpool.  A-frags hoisted ----
  short8_ A0[2][2], A1[2][2];
  #pragma unroll
  for (int mt = 0; mt < 2; ++mt)
    #pragma unroll
    for (int kt = 0; kt < 2; ++kt) {
      float4 x0 = *(const float4*)(Xf + (((mt*2+kt)*2+0)*256) + lane*4);
      float4 x1 = *(const float4*)(Xf + (((mt*2+kt)*2+1)*256) + lane*4);
      float f[8] = {x0.x,x0.y,x0.z,x0.w, x1.x,x1.y,x1.z,x1.w};
      bf2split8(f, A0[mt][kt], A1[mt][kt]);
    }
  float* outp = out + (size_t)(B_*S_)*3 + (size_t)bs*128;
  #pragma unroll
  for (int sub = 0; sub < 2; ++sub) {
    const int o = (wv*2 + sub)*16 + mcol;
    const float sc = scl[o];
    short8_ B0[2], B1[2];
    #pragma unroll
    for (int kt = 0; kt < 2; ++kt) {
      const float* wp = w2 + o*64 + kt*32 + quad*8;
      float4 u0 = *(const float4*)(wp);
      float4 u1 = *(const float4*)(wp + 4);
      float f[8] = {u0.x*sc,u0.y*sc,u0.z*sc,u0.w*sc,
                    u1.x*sc,u1.y*sc,u1.z*sc,u1.w*sc};
      bf2split8(f, B0[kt], B1[kt]);
    }
    float vmax = -3.0e38f;
    #pragma unroll
    for (int mt = 0; mt < 2; ++mt) {
      f32x4_ a = {0.f, 0.f, 0.f, 0.f};
      #pragma unroll
      for (int kt = 0; kt < 2; ++kt) {
        a = __builtin_amdgcn_mfma_f32_16x16x32_bf16(A0[mt][kt], B0[kt], a, 0,0,0);
        a = __builtin_amdgcn_mfma_f32_16x16x32_bf16(A0[mt][kt], B1[kt], a, 0,0,0);
        a = __builtin_amdgcn_mfma_f32_16x16x32_bf16(A1[mt][kt], B0[kt], a, 0,0,0);
      }
      vmax = fmaxf(vmax, fmaxf(fmaxf(a[0], a[1]), fmaxf(a[2], a[3])));
    }
    vmax = fmaxf(vmax, __shfl_xor(vmax, 16));
    vmax = fmaxf(vmax, __shfl_xor(vmax, 32));
    if (quad == 0) outp[o] = fmaxf(vmax + bia[o], 0.f);
  }
}

// =====================================================================
extern "C" void kernel_launch(void* const* d_in, const int* in_sizes, int n_in,
                              void* d_out, int out_size, void* d_ws, size_t ws_size,
                              hipStream_t stream)
{
  const float* xyz  = (const float*)d_in[0];
  const float* pts  = (const float*)d_in[1];
  const int*   sidx = (const int*)  d_in[2];
  const float* w0 = (const float*)d_in[3];
  const float* b0 = (const float*)d_in[4];
  const float* g0 = (const float*)d_in[5];
  const float* be0= (const float*)d_in[6];
  const float* m0 = (const float*)d_in[7];
  const float* v0 = (const float*)d_in[8];
  const float* w1 = (const float*)d_in[9];
  const float* b1 = (const float*)d_in[10];
  const float* g1 = (const float*)d_in[11];
  const float* be1= (const float*)d_in[12];
  const float* m1 = (const float*)d_in[13];
  const float* v1 = (const float*)d_in[14];
  const float* w2 = (const float*)d_in[15];
  const float* b2 = (const float*)d_in[16];
  const float* g2 = (const float*)d_in[17];
  const float* be2= (const float*)d_in[18];
  const float* m2 = (const float*)d_in[19];
  const float* v2 = (const float*)d_in[20];

  float* out = (float*)d_out;
  // ws: sqn (512KB) | nbr (2MB, reserved) | pw (16.8MB) | planes (3 x 16.78MB)
  float* sqn = (float*)d_ws;
  uint2* pw  = (uint2*)((char*)d_ws + (size_t)B_*N_*4 + (size_t)B_*S_*K_*4);
  char*  pl  = (char*)d_ws + (size_t)B_*N_*4 + (size_t)B_*S_*K_*4
             + (size_t)B_*S_*SPLIT_*32*8;
  short* P0 = (short*)pl;
  short* P1 = P0 + PLANE_;
  short* P2 = P1 + PLANE_;
  const size_t need = (size_t)B_*N_*4 + (size_t)B_*S_*K_*4
                    + (size_t)B_*S_*SPLIT_*32*8 + 3*PLANE_*2;

  if (ws_size >= need) {
    k_prep<<<(B_*N_)/256, 256, 0, stream>>>(xyz, pts, sidx, out, sqn, P0, P1, P2);
    k_knn <<<B_*32*SPLIT_, 256, 0, stream>>>(P0, P1, P2, sidx, sqn, pw);
  } else {
    k_prep_fb<<<(B_*N_)/256, 256, 0, stream>>>(xyz, pts, sidx, out, sqn);
    k_knn_fb <<<B_*32*SPLIT_, 256, 0, stream>>>(pts, sidx, sqn, pw);
  }
  k_mlp <<<B_*S_, 256, 0, stream>>>(pts, pw,
            w0,b0,g0,be0,m0,v0, w1,b1,g1,be1,m1,v1, w2,b2,g2,be2,m2,v2, out);
}

// Round 5
// 746.092 us; speedup vs baseline: 1.2466x; 1.0178x over previous
//
#include <hip/hip_runtime.h>

#define B_  8
#define N_  16384
#define D_  64
#define S_  2048
#define K_  32
#define SPLIT_  4
#define NSPL_   (N_/SPLIT_)       // 4096 candidates per block
#define CH32_   (NSPL_/32)        // 128 chunks of 32
#define PLANE_  ((size_t)B_*N_*64) // shorts per plane (8.39M = 16.78 MB)

using short8_ = __attribute__((ext_vector_type(8))) short;
using short4_ = __attribute__((ext_vector_type(4))) short;
using f32x4_  = __attribute__((ext_vector_type(4))) float;

// =====================================================================
// exact bf16 triple-split of fp32 (truncation-based): f = h0 + h1 + h2
// =====================================================================
__device__ __forceinline__ void bf3split(float f, short& h0, short& h1, short& h2)
{
  unsigned u0 = __float_as_uint(f);
  float f0 = __uint_as_float(u0 & 0xFFFF0000u);
  h0 = (short)(u0 >> 16);
  float r1 = f - f0;
  unsigned u1 = __float_as_uint(r1);
  float f1 = __uint_as_float(u1 & 0xFFFF0000u);
  h1 = (short)(u1 >> 16);
  float r2 = r1 - f1;                 // <= 8 significant bits: bf16-exact
  h2 = (short)(__float_as_uint(r2) >> 16);
}

// bf16 2-split of one float
__device__ __forceinline__ void bf2split1(float f, short& h0, short& h1)
{
  unsigned u = __float_as_uint(f);
  h0 = (short)(u >> 16);
  float r = f - __uint_as_float(u & 0xFFFF0000u);
  h1 = (short)(__float_as_uint(r) >> 16);
}

// bf16 2-split of 8 floats (fallback k_mlp_fb)
__device__ __forceinline__ void bf2split8(const float* f, short8_& h0, short8_& h1)
{
  #pragma unroll
  for (int j = 0; j < 8; ++j) {
    unsigned u = __float_as_uint(f[j]);
    h0[j] = (short)(u >> 16);
    float r = f[j] - __uint_as_float(u & 0xFFFF0000u);
    h1[j] = (short)(__float_as_uint(r) >> 16);
  }
}

// sorted-DESCENDING 32-entry list (Lv[0] = largest kept)
__device__ __forceinline__ void insert32(float (&Lv)[32], int (&Li)[32], float x, int n)
{
  bool ci = x < Lv[0];
  #pragma unroll
  for (int i = 0; i < 31; ++i) {
    bool c1 = x < Lv[i+1];
    float nv = c1 ? Lv[i+1] : (ci ? x : Lv[i]);
    int   ni = c1 ? Li[i+1] : (ci ? n : Li[i]);
    Lv[i] = nv; Li[i] = ni;
    ci = c1;
  }
  Lv[31] = ci ? x : Lv[31];
  Li[31] = ci ? n : Li[31];
}

// =====================================================================
// K1 (fast path): sqn + new_xyz gather + fragment-major bf16x3 planes
// r15: ALSO precomputes BN-folded, bf16-2-split MLP weights + biases
// into workspace (identical float ops as the old per-block k_mlp fold
// -> bit-identical bf16 pairs).  sqn: EXACT round-3 expression.
// =====================================================================
__global__ __launch_bounds__(256) void k_prep(
    const float* __restrict__ xyz, const float* __restrict__ points,
    const int* __restrict__ sidx, float* __restrict__ out, float* __restrict__ sqn,
    short* __restrict__ P0, short* __restrict__ P1, short* __restrict__ P2,
    const float* __restrict__ w0, const float* __restrict__ b0,
    const float* __restrict__ g0, const float* __restrict__ be0,
    const float* __restrict__ m0, const float* __restrict__ v0,
    const float* __restrict__ w1, const float* __restrict__ b1,
    const float* __restrict__ g1, const float* __restrict__ be1,
    const float* __restrict__ m1, const float* __restrict__ v1,
    const float* __restrict__ w2, const float* __restrict__ b2,
    const float* __restrict__ g2, const float* __restrict__ be2,
    const float* __restrict__ m2, const float* __restrict__ v2,
    short* __restrict__ Ws0_0, short* __restrict__ Ws0_1,
    short* __restrict__ Ws1_0, short* __restrict__ Ws1_1,
    short* __restrict__ Ws2_0, short* __restrict__ Ws2_1,
    float* __restrict__ bia0, float* __restrict__ bia1, float* __restrict__ bia2)
{
  int tid = blockIdx.x * 256 + threadIdx.x;      // 0 .. B*N-1
  const float4* p = (const float4*)(points + (size_t)tid * 64);

  float s = 0.f;
  #pragma unroll
  for (int i = 0; i < 16; ++i) {
    float4 v = p[i];
    s += v.x*v.x + v.y*v.y + v.z*v.z + v.w*v.w;
  }
  sqn[tid] = s;

  int n = tid & (N_-1);
  int c = n >> 6, ct = (n >> 4) & 3, mc = n & 15;
  size_t segbase = (((size_t)(tid >> 14) * 256 + c) * 4 + ct) * 2;  // *512 shorts

  #pragma unroll
  for (int g = 0; g < 8; ++g) {                  // (kt=g>>2, qd=g&3), dims 8g..8g+7
    float4 a = p[2*g], b4 = p[2*g+1];
    float f[8] = {a.x,a.y,a.z,a.w, b4.x,b4.y,b4.z,b4.w};
    short8_ h0v, h1v, h2v;
    #pragma unroll
    for (int j = 0; j < 8; ++j) {
      short h0, h1, h2;
      bf3split(f[j], h0, h1, h2);
      h0v[j] = h0; h1v[j] = h1; h2v[j] = h2;
    }
    size_t off = ((segbase + (g>>2))*64 + (size_t)(g&3)*16 + mc)*8;
    *(short8_*)(P0 + off) = h0v;
    *(short8_*)(P1 + off) = h1v;
    *(short8_*)(P2 + off) = h2v;
  }
  if (tid < B_*S_) {
    int b = tid >> 11, ss = tid & (S_-1);
    int nn = sidx[ss];
    const float* src = xyz + ((size_t)b * N_ + nn) * 3;
    out[(size_t)tid*3+0] = src[0];
    out[(size_t)tid*3+1] = src[1];
    out[(size_t)tid*3+2] = src[2];
  }
  // ---- weight pre-scale + 2-split (same ops as old per-block fold) ----
  if (tid < 16384) {
    float wval, sc; short *d0, *d1; int i = tid;
    if (tid < 4096) {
      int o = tid >> 6;
      sc = g0[o] * rsqrtf(v0[o] + 1e-5f);
      wval = w0[tid]; d0 = Ws0_0; d1 = Ws0_1;
    } else if (tid < 8192) {
      i = tid - 4096; int o = i >> 6;
      sc = g1[o] * rsqrtf(v1[o] + 1e-5f);
      wval = w1[i]; d0 = Ws1_0; d1 = Ws1_1;
    } else {
      i = tid - 8192; int o = i >> 6;
      sc = g2[o] * rsqrtf(v2[o] + 1e-5f);
      wval = w2[i]; d0 = Ws2_0; d1 = Ws2_1;
    }
    short h0, h1;
    bf2split1(wval * sc, h0, h1);
    d0[i] = h0; d1[i] = h1;
  }
  if (tid < 256) {
    if (tid < 64) {
      float sc = g0[tid] * rsqrtf(v0[tid] + 1e-5f);
      bia0[tid] = (b0[tid] - m0[tid]) * sc + be0[tid];
    } else if (tid < 128) {
      int j = tid - 64;
      float sc = g1[j] * rsqrtf(v1[j] + 1e-5f);
      bia1[j] = (b1[j] - m1[j]) * sc + be1[j];
    } else {
      int j = tid - 128;
      float sc = g2[j] * rsqrtf(v2[j] + 1e-5f);
      bia2[j] = (b2[j] - m2[j]) * sc + be2[j];
    }
  }
}

// =====================================================================
// K2 (fast path), r15 == r14 VERBATIM (control: counters must match).
// =====================================================================
__global__ __launch_bounds__(256) void k_knn(
    const short* __restrict__ P0, const short* __restrict__ P1,
    const short* __restrict__ P2, const int* __restrict__ sidx,
    const float* __restrict__ sqn, uint2* __restrict__ pw)
{
  // LDS: Dtr [64r][36c] 9216 | qbuf 16384 @9216 (total 25600)
  // merge phase aliases front as uint2 mbuf[32][130] = 33280 (all dead then)
  __shared__ __align__(16) char smraw[33280];
  float* Dtr = (float*)smraw;
  uint2* qb  = (uint2*)(smraw + 9216);   // [8 slots][256 lanes]

  const int t = threadIdx.x;
  const int b     = blockIdx.x & 7;          // XCD swizzle
  const int y     = blockIdx.x >> 3;
  const int tile  = y & 31;
  const int split = y >> 5;
  const int s0 = tile * 64;
  const float* Qb = sqn + (size_t)b * N_;

  const int lane = t & 63, wv = t >> 6;
  const int quad = lane >> 4, mcol = lane & 15;

  // ---- A fragments (wave wv owns sampled rows 16*wv..+15), from planes ----
  short8_ A0[2], A1[2], A2[2];
  {
    int srow = sidx[s0 + 16*wv + mcol];
    int cs = srow >> 6, cts = (srow >> 4) & 3, ms = srow & 15;
    size_t ab = (((size_t)(b*256 + cs))*4 + cts)*2*512 + ((size_t)quad*16 + ms)*8;
    #pragma unroll
    for (int kt = 0; kt < 2; ++kt) {
      A0[kt] = *(const short8_*)(P0 + ab + kt*512);
      A1[kt] = *(const short8_*)(P1 + ab + kt*512);
      A2[kt] = *(const short8_*)(P2 + ab + kt*512);
    }
  }

  float Lv[32]; int Li[32];
  #pragma unroll
  for (int i = 0; i < 32; ++i) { Lv[i] = 3.0e38f; Li[i] = 0; }

  const int r = t >> 2;        // selection row 0..63
  const int q = t & 3;         // stream within row
  const int n0base = split * NSPL_;
  const size_t bc8base = (size_t)b * 256;

  int qhead = 0, qtail = 0;    // per-lane FIFO state

  // selection pass for the chunk whose keys sit in Dtr (wave-private rows)
  auto do_select = [&](int n0sel) {
    // ---- adaptive drain: pass only when some lane has >=2 pending ----
    if (__any((qtail - qhead) >= 2)) {
      if (qhead < qtail) {
        uint2 e = qb[(qhead & 7)*256 + t];
        qhead++;
        float x = __uint_as_float(e.x);
        if (x < Lv[0])
          insert32(Lv, Li, x, (int)e.y);
      }
    }
    // ---- admission: exact bounds (t24 + own 32nd), cheap FIFO pushes ----
    float ownL0 = Lv[0];
    float t24 = Lv[24];                       // stream 8th-smallest
    t24 = fmaxf(t24, __shfl_xor(t24, 1));
    t24 = fmaxf(t24, __shfl_xor(t24, 2));     // max over streams: row-32nd <= t24
    const float thr = fminf(t24, ownL0);

    float4 ka = *(const float4*)(Dtr + r*36 + q*8);
    float4 kb = *(const float4*)(Dtr + r*36 + q*8 + 4);
    float x8[8] = {ka.x,ka.y,ka.z,ka.w, kb.x,kb.y,kb.z,kb.w};
    unsigned m = 0;
    #pragma unroll
    for (int i = 0; i < 8; ++i)
      m |= (x8[i] < thr) ? (1u << i) : 0u;
    while (m) {                               // per-lane, cheap body
      int i = __ffs(m) - 1;
      m &= m - 1;
      float xlo = (i & 1) ? ((i & 2) ? x8[3] : x8[1]) : ((i & 2) ? x8[2] : x8[0]);
      float xhi = (i & 1) ? ((i & 2) ? x8[7] : x8[5]) : ((i & 2) ? x8[6] : x8[4]);
      float x = (i & 4) ? xhi : xlo;
      if (qtail - qhead >= 8) {               // full: drain one in-place (rare)
        uint2 e = qb[(qhead & 7)*256 + t];
        qhead++;
        float xe = __uint_as_float(e.x);
        if (xe < Lv[0])
          insert32(Lv, Li, xe, (int)e.y);
      }
      qb[(qtail & 7)*256 + t] = make_uint2(__float_as_uint(x), (unsigned)(n0sel + q*8 + i));
      qtail++;
    }
  };

  // running plane offset for chunk 0 (n0base % 64 == 0)
  size_t goff = ((bc8base + (size_t)(n0base >> 6)) * 8) * 512 + (size_t)lane * 8;

  short8_ b0[2][2], b1[2][2], b2[2][2];   // [ct][kt]
  float sq0, sq1;

  auto kload = [&](int n0c) {
    #pragma unroll
    for (int s = 0; s < 4; ++s) {           // s = ct*2 + kt
      b0[s>>1][s&1] = *(const short8_*)(P0 + goff + (size_t)s*512);
      b1[s>>1][s&1] = *(const short8_*)(P1 + goff + (size_t)s*512);
      b2[s>>1][s&1] = *(const short8_*)(P2 + goff + (size_t)s*512);
    }
    sq0 = Qb[n0c + mcol];                   // ct=0 column sqnorm
    sq1 = Qb[n0c + 16 + mcol];              // ct=1 column sqnorm
    goff += 2048;                           // 4 slots x 512 shorts per chunk
  };

  auto kmfma = [&]() {
    #pragma unroll
    for (int ct = 0; ct < 2; ++ct) {
      f32x4_ a = {0.f, 0.f, 0.f, 0.f};
      #pragma unroll
      for (int kt = 0; kt < 2; ++kt) {
        a = __builtin_amdgcn_mfma_f32_16x16x32_bf16(A0[kt], b0[ct][kt], a, 0,0,0);
        a = __builtin_amdgcn_mfma_f32_16x16x32_bf16(A0[kt], b1[ct][kt], a, 0,0,0);
        a = __builtin_amdgcn_mfma_f32_16x16x32_bf16(A1[kt], b0[ct][kt], a, 0,0,0);
        a = __builtin_amdgcn_mfma_f32_16x16x32_bf16(A1[kt], b1[ct][kt], a, 0,0,0);
        a = __builtin_amdgcn_mfma_f32_16x16x32_bf16(A0[kt], b2[ct][kt], a, 0,0,0);
        a = __builtin_amdgcn_mfma_f32_16x16x32_bf16(A2[kt], b0[ct][kt], a, 0,0,0);
        a = __builtin_amdgcn_mfma_f32_16x16x32_bf16(A1[kt], b2[ct][kt], a, 0,0,0);
        a = __builtin_amdgcn_mfma_f32_16x16x32_bf16(A2[kt], b1[ct][kt], a, 0,0,0);
      }
      // keys -> Dtr (wave-local rows). C/D: col=lane&15, row=quad*4+reg
      int cc = 16*ct + mcol;
      float sq = ct ? sq1 : sq0;
      int rb = 16*wv + 4*quad;
      Dtr[(rb+0)*36 + cc] = sq - 2.f*a[0];
      Dtr[(rb+1)*36 + cc] = sq - 2.f*a[1];
      Dtr[(rb+2)*36 + cc] = sq - 2.f*a[2];
      Dtr[(rb+3)*36 + cc] = sq - 2.f*a[3];
    }
    // no barrier anywhere: Dtr rows 16wv..16wv+15 are wave-private (lgkmcnt)
  };

  // direct fill of list slots 8J..8J+7 from Dtr (chunk J's keys); static J
  #define FILLJ(J) { \
    float4 ka = *(const float4*)(Dtr + r*36 + q*8); \
    float4 kb = *(const float4*)(Dtr + r*36 + q*8 + 4); \
    float x8f[8] = {ka.x,ka.y,ka.z,ka.w, kb.x,kb.y,kb.z,kb.w}; \
    _Pragma("unroll") \
    for (int i = 0; i < 8; ++i) { \
      Lv[(J)*8 + i] = x8f[i]; \
      Li[(J)*8 + i] = n0base + (J)*32 + q*8 + i; } }

  // ---- prologue: chunks 0-4; fills for 0-3, one sort, then steady ----
  kload(n0base + 0*32);            kmfma();
  kload(n0base + 1*32); FILLJ(0);  kmfma();
  kload(n0base + 2*32); FILLJ(1);  kmfma();
  kload(n0base + 3*32); FILLJ(2);  kmfma();
  kload(n0base + 4*32); FILLJ(3);
  // bitonic sort, (v,idx)-lex DESCENDING (pos 0 = greatest) == insert32 order
  #pragma unroll
  for (int k = 2; k <= 32; k <<= 1) {
    #pragma unroll
    for (int j2 = k >> 1; j2 > 0; j2 >>= 1) {
      #pragma unroll
      for (int i = 0; i < 32; ++i) {
        int l = i ^ j2;
        if (l > i) {
          bool g = (Lv[l] > Lv[i]) || (Lv[l] == Lv[i] && Li[l] > Li[i]);
          bool sw = ((i & k) == 0) ? g : !g;
          float tv = sw ? Lv[l] : Lv[i];
          float uv = sw ? Lv[i] : Lv[l];
          int   ti = sw ? Li[l] : Li[i];
          int   ui = sw ? Li[i] : Li[l];
          Lv[i] = tv; Lv[l] = uv; Li[i] = ti; Li[l] = ui;
        }
      }
    }
  }
  kmfma();

  // ---- steady loop: verbatim r11 body ----
  for (int ch = 5; ch < CH32_; ++ch) {
    kload(n0base + ch*32);
    do_select(n0base + ch*32 - 32);
    kmfma();
  }
  do_select(n0base + NSPL_ - 32);           // selection for the last chunk

  // ---- final drain ----
  while (__any(qhead < qtail)) {
    if (qhead < qtail) {
      uint2 e = qb[(qhead & 7)*256 + t];
      qhead++;
      float x = __uint_as_float(e.x);
      if (x < Lv[0])
        insert32(Lv, Li, x, (int)e.y);
    }
  }

  // ---- in-block 4-pointer merge (streams stored reversed -> ascending) ----
  uint2* mbuf = (uint2*)smraw;                 // [32][130]
  const int rowg = b * S_ + s0;
  for (int pass = 0; pass < 2; ++pass) {
    __syncthreads();
    const int rb = pass * 32;
    if (r >= rb && r < rb + 32) {
      #pragma unroll
      for (int i = 0; i < 32; ++i)
        mbuf[(r - rb)*130 + q*32 + (31 - i)] =
            make_uint2(__float_as_uint(Lv[i]), (unsigned)Li[i]);
    }
    __syncthreads();
    if (t < 32) {
      const uint2* Lrow = mbuf + t*130;
      uint2* dst = pw + ((size_t)(rowg + rb + t) * SPLIT_ + split) * 32;
      int p0 = 0, p1 = 0, p2 = 0, p3 = 0;
      for (int k = 0; k < 32; ++k) {
        float bv = 3.0e38f; unsigned bi = 0xFFFFFFFFu; int bq = 0;
        int pa[4] = {p0, p1, p2, p3};
        #pragma unroll
        for (int q4 = 0; q4 < 4; ++q4) {
          if (pa[q4] < 32) {
            uint2 e = Lrow[q4*32 + pa[q4]];
            float v = __uint_as_float(e.x);
            if (v < bv || (v == bv && e.y < bi)) { bv = v; bi = e.y; bq = q4; }
          }
        }
        dst[k] = make_uint2(__float_as_uint(bv), bi);
        if (bq == 0) p0++; else if (bq == 1) p1++; else if (bq == 2) p2++; else p3++;
      }
    }
  }
  #undef FILLJ
}

// =====================================================================
// FALLBACK path (ws too small): round-3 kernels, proven correct
// =====================================================================
__global__ __launch_bounds__(256) void k_prep_fb(
    const float* __restrict__ xyz, const float* __restrict__ points,
    const int* __restrict__ sidx, float* __restrict__ out, float* __restrict__ sqn)
{
  int tid = blockIdx.x * 256 + threadIdx.x;
  const float4* p = (const float4*)(points + (size_t)tid * 64);
  float s = 0.f;
  #pragma unroll
  for (int i = 0; i < 16; ++i) {
    float4 v = p[i];
    s += v.x*v.x + v.y*v.y + v.z*v.z + v.w*v.w;
  }
  sqn[tid] = s;
  if (tid < B_*S_) {
    int b = tid >> 11, ss = tid & (S_-1);
    int n = sidx[ss];
    const float* src = xyz + ((size_t)b * N_ + n) * 3;
    out[(size_t)tid*3+0] = src[0];
    out[(size_t)tid*3+1] = src[1];
    out[(size_t)tid*3+2] = src[2];
  }
}

__global__ __launch_bounds__(256) void k_knn_fb(
    const float* __restrict__ points, const int* __restrict__ sidx,
    const float* __restrict__ sqn, uint2* __restrict__ pw)
{
  __shared__ __align__(16) char smraw[45312];
  short* Bp0 = (short*)smraw;
  short* Bp1 = (short*)(smraw + 9216);
  short* Bp2 = (short*)(smraw + 18432);
  float* Dt  = (float*)(smraw + 27648);
  float* sqc = (float*)(smraw + 45056);

  const int t = threadIdx.x;
  const int b     = blockIdx.x & 7;
  const int y     = blockIdx.x >> 3;
  const int tile  = y & 31;
  const int split = y >> 5;
  const int s0 = tile * 64;
  const float* Pb = points + (size_t)b * N_ * 64;
  const float* Qb = sqn    + (size_t)b * N_;

  const int lane = t & 63, wv = t >> 6;
  const int quad = lane >> 4, mcol = lane & 15;

  short8_ A0[2], A1[2], A2[2];
  {
    int srow = sidx[s0 + 16*wv + mcol];
    const float* ar = Pb + (size_t)srow * 64;
    #pragma unroll
    for (int kt = 0; kt < 2; ++kt) {
      float4 v0 = *(const float4*)(ar + 32*kt + 8*quad);
      float4 v1 = *(const float4*)(ar + 32*kt + 8*quad + 4);
      float f[8] = {v0.x,v0.y,v0.z,v0.w,v1.x,v1.y,v1.z,v1.w};
      #pragma unroll
      for (int j = 0; j < 8; ++j) {
        short h0, h1, h2;
        bf3split(f[j], h0, h1, h2);
        A0[kt][j] = h0; A1[kt][j] = h1; A2[kt][j] = h2;
      }
    }
  }

  float Lv[32]; int Li[32];
  #pragma unroll
  for (int i = 0; i < 32; ++i) { Lv[i] = 3.0e38f; Li[i] = 0; }

  const int r = t >> 2;
  const int q = t & 3;
  const int n0base = split * NSPL_;

  for (int ch = 0; ch < NSPL_/64; ++ch) {
    const int n0 = n0base + ch * 64;
    {
      const int n = t & 63, jg = t >> 6;
      const float* src = Pb + (size_t)(n0 + n) * 64 + 16*jg;
      float4 u0 = *(const float4*)(src);
      float4 u1 = *(const float4*)(src + 4);
      float4 u2 = *(const float4*)(src + 8);
      float4 u3 = *(const float4*)(src + 12);
      float f[16] = {u0.x,u0.y,u0.z,u0.w, u1.x,u1.y,u1.z,u1.w,
                     u2.x,u2.y,u2.z,u2.w, u3.x,u3.y,u3.z,u3.w};
      short8_ p0[2], p1[2], p2[2];
      #pragma unroll
      for (int j = 0; j < 16; ++j) {
        short h0, h1, h2;
        bf3split(f[j], h0, h1, h2);
        p0[j>>3][j&7] = h0; p1[j>>3][j&7] = h1; p2[j>>3][j&7] = h2;
      }
      *(short8_*)(Bp0 + n*72 + 16*jg)     = p0[0];
      *(short8_*)(Bp0 + n*72 + 16*jg + 8) = p0[1];
      *(short8_*)(Bp1 + n*72 + 16*jg)     = p1[0];
      *(short8_*)(Bp1 + n*72 + 16*jg + 8) = p1[1];
      *(short8_*)(Bp2 + n*72 + 16*jg)     = p2[0];
      *(short8_*)(Bp2 + n*72 + 16*jg + 8) = p2[1];
      if (t < 16) *(float4*)(sqc + 4*t) = *(const float4*)(Qb + n0 + 4*t);
    }
    __syncthreads();

    f32x4_ acc[4];
    #pragma unroll
    for (int ct = 0; ct < 4; ++ct) {
      const int boff = (16*ct + mcol)*72 + 8*quad;
      short8_ b0[2], b1[2], b2[2];
      b0[0] = *(const short8_*)(Bp0 + boff); b0[1] = *(const short8_*)(Bp0 + boff + 32);
      b1[0] = *(const short8_*)(Bp1 + boff); b1[1] = *(const short8_*)(Bp1 + boff + 32);
      b2[0] = *(const short8_*)(Bp2 + boff); b2[1] = *(const short8_*)(Bp2 + boff + 32);
      f32x4_ a = {0.f, 0.f, 0.f, 0.f};
      #pragma unroll
      for (int kt = 0; kt < 2; ++kt) {
        a = __builtin_amdgcn_mfma_f32_16x16x32_bf16(A0[kt], b0[kt], a, 0,0,0);
        a = __builtin_amdgcn_mfma_f32_16x16x32_bf16(A0[kt], b1[kt], a, 0,0,0);
        a = __builtin_amdgcn_mfma_f32_16x16x32_bf16(A1[kt], b0[kt], a, 0,0,0);
        a = __builtin_amdgcn_mfma_f32_16x16x32_bf16(A1[kt], b1[kt], a, 0,0,0);
        a = __builtin_amdgcn_mfma_f32_16x16x32_bf16(A0[kt], b2[kt], a, 0,0,0);
        a = __builtin_amdgcn_mfma_f32_16x16x32_bf16(A2[kt], b0[kt], a, 0,0,0);
        a = __builtin_amdgcn_mfma_f32_16x16x32_bf16(A1[kt], b2[kt], a, 0,0,0);
        a = __builtin_amdgcn_mfma_f32_16x16x32_bf16(A2[kt], b1[kt], a, 0,0,0);
      }
      acc[ct] = a;
    }
    #pragma unroll
    for (int ct = 0; ct < 4; ++ct) {
      int c = 16*ct + mcol;
      float sq = sqc[c];
      float4 kv;
      kv.x = sq - 2.f*acc[ct][0];
      kv.y = sq - 2.f*acc[ct][1];
      kv.z = sq - 2.f*acc[ct][2];
      kv.w = sq - 2.f*acc[ct][3];
      *(float4*)(Dt + c*68 + 16*wv + 4*quad) = kv;
    }
    __syncthreads();

    float L0 = Lv[0];
    L0 = fminf(L0, __shfl_xor(L0, 1));
    L0 = fminf(L0, __shfl_xor(L0, 2));
    const float tau = L0;
    #pragma unroll
    for (int g = 0; g < 4; ++g) {
      #pragma unroll
      for (int u = 0; u < 4; ++u) {
        int c = q*16 + g*4 + u;
        float x = Dt[c*68 + r];
        if (x < fminf(tau, Lv[0]))
          insert32(Lv, Li, x, n0 + c);
      }
    }
  }

  uint2* mbuf = (uint2*)smraw;
  const int rowg = b * S_ + s0;
  for (int pass = 0; pass < 2; ++pass) {
    __syncthreads();
    const int rb = pass * 32;
    if (r >= rb && r < rb + 32) {
      #pragma unroll
      for (int i = 0; i < 32; ++i)
        mbuf[(r - rb)*130 + q*32 + (31 - i)] =
            make_uint2(__float_as_uint(Lv[i]), (unsigned)Li[i]);
    }
    __syncthreads();
    if (t < 32) {
      const uint2* Lrow = mbuf + t*130;
      uint2* dst = pw + ((size_t)(rowg + rb + t) * SPLIT_ + split) * 32;
      int p0 = 0, p1 = 0, p2 = 0, p3 = 0;
      for (int k = 0; k < 32; ++k) {
        float bv = 3.0e38f; unsigned bi = 0xFFFFFFFFu; int bq = 0;
        int pa[4] = {p0, p1, p2, p3};
        #pragma unroll
        for (int q4 = 0; q4 < 4; ++q4) {
          if (pa[q4] < 32) {
            uint2 e = Lrow[q4*32 + pa[q4]];
            float v = __uint_as_float(e.x);
            if (v < bv || (v == bv && e.y < bi)) { bv = v; bi = e.y; bq = q4; }
          }
        }
        dst[k] = make_uint2(__float_as_uint(bv), bi);
        if (bq == 0) p0++; else if (bq == 1) p1++; else if (bq == 2) p2++; else p3++;
      }
    }
  }
}

// =====================================================================
// K3 (fast path), r15: MFMA MLP with PRE-SPLIT weights (global, from
// k_prep) and PRE-SPLIT activations (LDS, split once at write time).
// Consumer-side bf2split is eliminated; A-fragments are contiguous
// 16B ds_read_b128.  Numerics bit-identical: same float products,
// same truncation splits, same MFMA order.
// LDS act layout: Xa[seg=(mt*2+kt)][lane][8] shorts, +h*4+e within.
// =====================================================================
__device__ __forceinline__ void layer_pre(
    int lane, int wv, const short* Xa0, const short* Xa1,
    short* Ha0, short* Ha1,
    const short* __restrict__ Ws0, const short* __restrict__ Ws1,
    const float* __restrict__ biaP)
{
  const int quad = lane >> 4, mcol = lane & 15;
  const int o = wv*16 + mcol;                 // this wave's output column
  short8_ B0[2], B1[2];
  #pragma unroll
  for (int kt = 0; kt < 2; ++kt) {
    B0[kt] = *(const short8_*)(Ws0 + o*64 + kt*32 + quad*8);
    B1[kt] = *(const short8_*)(Ws1 + o*64 + kt*32 + quad*8);
  }
  const float bo = biaP[o];
  const int kt2 = (o >> 5) & 1, qk2 = (o >> 3) & 3, h2 = (o >> 2) & 1, j2 = o & 3;
  #pragma unroll
  for (int mt = 0; mt < 2; ++mt) {
    short8_ A0[2], A1[2];
    #pragma unroll
    for (int kt = 0; kt < 2; ++kt) {
      A0[kt] = *(const short8_*)(Xa0 + ((mt*2+kt)*64 + lane)*8);
      A1[kt] = *(const short8_*)(Xa1 + ((mt*2+kt)*64 + lane)*8);
    }
    f32x4_ a = {0.f, 0.f, 0.f, 0.f};
    #pragma unroll
    for (int kt = 0; kt < 2; ++kt) {
      a = __builtin_amdgcn_mfma_f32_16x16x32_bf16(A0[kt], B0[kt], a, 0,0,0);
      a = __builtin_amdgcn_mfma_f32_16x16x32_bf16(A0[kt], B1[kt], a, 0,0,0);
      a = __builtin_amdgcn_mfma_f32_16x16x32_bf16(A1[kt], B0[kt], a, 0,0,0);
    }
    #pragma unroll
    for (int reg = 0; reg < 4; ++reg) {
      int ml = quad*4 + reg;                  // m within mtile
      float hval = fmaxf(a[reg] + bo, 0.f);
      short h0, h1;
      bf2split1(hval, h0, h1);
      int idx = ((mt*2 + kt2)*64 + qk2*16 + ml)*8 + h2*4 + j2;
      Ha0[idx] = h0;
      Ha1[idx] = h1;
    }
  }
}

__global__ __launch_bounds__(256) void k_mlp(
    const float* __restrict__ points, const uint2* __restrict__ pw,
    const short* __restrict__ Ws0_0, const short* __restrict__ Ws0_1,
    const short* __restrict__ Ws1_0, const short* __restrict__ Ws1_1,
    const short* __restrict__ Ws2_0, const short* __restrict__ Ws2_1,
    const float* __restrict__ bia0, const float* __restrict__ bia1,
    const float* __restrict__ bia2, float* __restrict__ out)
{
  __shared__ __align__(16) short Xa0[2048];  // acts plane h0 (4KB)
  __shared__ __align__(16) short Xa1[2048];  // acts plane h1
  __shared__ __align__(16) short Ha0[2048];
  __shared__ __align__(16) short Ha1[2048];
  __shared__ int   nIx[32];
  __shared__ __align__(8) uint2 Lr[128];     // row's 4 sorted 32-lists

  const int t  = threadIdx.x;
  const int bs = blockIdx.x;
  const int b  = bs >> 11;
  const int lane = t & 63, wv = t >> 6;
  const int quad = lane >> 4, mcol = lane & 15;

  // ---- fused k_sel prelude: parallel rank-select over 4 sorted lists ----
  if (t < 128) Lr[t] = pw[(size_t)bs * (SPLIT_*32) + t];
  __syncthreads();
  if (t < 128) {
    uint2 e = Lr[t];
    float ev = __uint_as_float(e.x);
    int rank = t & 31;                       // own position in own list
    #pragma unroll
    for (int oq = 1; oq < 4; ++oq) {
      const uint2* L = Lr + ((((t >> 5) + oq) & 3) << 5);
      int lo = 0;
      #pragma unroll
      for (int stp = 16; stp > 0; stp >>= 1) {
        uint2 c = L[lo + stp - 1];
        float cv = __uint_as_float(c.x);
        bool lt = (cv < ev) || (cv == ev && c.y < e.y);
        lo += lt ? stp : 0;
      }
      { // final correction: count may be up to 32
        uint2 c = L[lo];
        float cv = __uint_as_float(c.x);
        bool lt = (cv < ev) || (cv == ev && c.y < e.y);
        lo += lt ? 1 : 0;
      }
      rank += lo;
    }
    if (rank < 32) nIx[rank] = (int)e.y;
  }
  __syncthreads();
  // stage X (32 rows x 64 ch fp32), split ONCE into Xa0/Xa1
  #pragma unroll
  for (int rep = 0; rep < 2; ++rep) {
    int task = rep*256 + t;
    int row = task >> 4, j4 = task & 15;
    float4 v = *(const float4*)(points + ((size_t)b*N_ + nIx[row])*64 + j4*4);
    int kt = j4 >> 3, qk = (j4 >> 1) & 3, h = j4 & 1;
    int base = (((row>>4)*2 + kt)*64 + qk*16 + (row&15))*8 + h*4;
    float f4[4] = {v.x, v.y, v.z, v.w};
    short4_ s0v, s1v;
    #pragma unroll
    for (int e = 0; e < 4; ++e) {
      short h0, h1;
      bf2split1(f4[e], h0, h1);
      s0v[e] = h0; s1v[e] = h1;
    }
    *(short4_*)(Xa0 + base) = s0v;
    *(short4_*)(Xa1 + base) = s1v;
  }
  __syncthreads();

  layer_pre(lane, wv, Xa0, Xa1, Ha0, Ha1, Ws0_0, Ws0_1, bia0);  // X -> H
  __syncthreads();
  layer_pre(lane, wv, Ha0, Ha1, Xa0, Xa1, Ws1_0, Ws1_1, bia1);  // H -> X'
  __syncthreads();

  // ---- layer 2: 64 -> 128, fused maxpool.  A-frags hoisted ----
  short8_ A0[2][2], A1[2][2];
  #pragma unroll
  for (int mt = 0; mt < 2; ++mt)
    #pragma unroll
    for (int kt = 0; kt < 2; ++kt) {
      A0[mt][kt] = *(const short8_*)(Xa0 + ((mt*2+kt)*64 + lane)*8);
      A1[mt][kt] = *(const short8_*)(Xa1 + ((mt*2+kt)*64 + lane)*8);
    }
  float* outp = out + (size_t)(B_*S_)*3 + (size_t)bs*128;
  #pragma unroll
  for (int sub = 0; sub < 2; ++sub) {
    const int o = (wv*2 + sub)*16 + mcol;
    short8_ B0[2], B1[2];
    #pragma unroll
    for (int kt = 0; kt < 2; ++kt) {
      B0[kt] = *(const short8_*)(Ws2_0 + o*64 + kt*32 + quad*8);
      B1[kt] = *(const short8_*)(Ws2_1 + o*64 + kt*32 + quad*8);
    }
    float vmax = -3.0e38f;
    #pragma unroll
    for (int mt = 0; mt < 2; ++mt) {
      f32x4_ a = {0.f, 0.f, 0.f, 0.f};
      #pragma unroll
      for (int kt = 0; kt < 2; ++kt) {
        a = __builtin_amdgcn_mfma_f32_16x16x32_bf16(A0[mt][kt], B0[kt], a, 0,0,0);
        a = __builtin_amdgcn_mfma_f32_16x16x32_bf16(A0[mt][kt], B1[kt], a, 0,0,0);
        a = __builtin_amdgcn_mfma_f32_16x16x32_bf16(A1[mt][kt], B0[kt], a, 0,0,0);
      }
      vmax = fmaxf(vmax, fmaxf(fmaxf(a[0], a[1]), fmaxf(a[2], a[3])));
    }
    vmax = fmaxf(vmax, __shfl_xor(vmax, 16));
    vmax = fmaxf(vmax, __shfl_xor(vmax, 32));
    if (quad == 0) outp[o] = fmaxf(vmax + bia2[o], 0.f);
  }
}

// =====================================================================
// K3 FALLBACK: old per-block-fold k_mlp (r13), used when ws lacks planes
// =====================================================================
__device__ __forceinline__ void layer_mfma(
    int lane, int wv, const float* Xf, float* Hf,
    const float* __restrict__ wgt, const float* scl, const float* bia)
{
  const int quad = lane >> 4, mcol = lane & 15;
  const int o = wv*16 + mcol;
  const float sc = scl[o];
  short8_ B0[2], B1[2];
  #pragma unroll
  for (int kt = 0; kt < 2; ++kt) {
    const float* wp = wgt + o*64 + kt*32 + quad*8;
    float4 u0 = *(const float4*)(wp);
    float4 u1 = *(const float4*)(wp + 4);
    float f[8] = {u0.x*sc,u0.y*sc,u0.z*sc,u0.w*sc,
                  u1.x*sc,u1.y*sc,u1.z*sc,u1.w*sc};
    bf2split8(f, B0[kt], B1[kt]);
  }
  const float bo = bia[o];
  const int kt2 = (o >> 5) & 1, qk2 = (o >> 3) & 3, h2 = (o >> 2) & 1, j2 = o & 3;
  #pragma unroll
  for (int mt = 0; mt < 2; ++mt) {
    short8_ A0[2], A1[2];
    #pragma unroll
    for (int kt = 0; kt < 2; ++kt) {
      float4 x0 = *(const float4*)(Xf + (((mt*2+kt)*2+0)*256) + lane*4);
      float4 x1 = *(const float4*)(Xf + (((mt*2+kt)*2+1)*256) + lane*4);
      float f[8] = {x0.x,x0.y,x0.z,x0.w, x1.x,x1.y,x1.z,x1.w};
      bf2split8(f, A0[kt], A1[kt]);
    }
    f32x4_ a = {0.f, 0.f, 0.f, 0.f};
    #pragma unroll
    for (int kt = 0; kt < 2; ++kt) {
      a = __builtin_amdgcn_mfma_f32_16x16x32_bf16(A0[kt], B0[kt], a, 0,0,0);
      a = __builtin_amdgcn_mfma_f32_16x16x32_bf16(A0[kt], B1[kt], a, 0,0,0);
      a = __builtin_amdgcn_mfma_f32_16x16x32_bf16(A1[kt], B0[kt], a, 0,0,0);
    }
    #pragma unroll
    for (int reg = 0; reg < 4; ++reg) {
      int ml = quad*4 + reg;
      float hval = fmaxf(a[reg] + bo, 0.f);
      Hf[((mt*2 + kt2)*2 + h2)*256 + (qk2*16 + ml)*4 + j2] = hval;
    }
  }
}

__global__ __launch_bounds__(256) void k_mlp_fb(
    const float* __restrict__ points, const uint2* __restrict__ pw,
    const float* __restrict__ w0, const float* __restrict__ b0,
    const float* __restrict__ g0, const float* __restrict__ be0,
    const float* __restrict__ m0, const float* __restrict__ v0,
    const float* __restrict__ w1, const float* __restrict__ b1,
    const float* __restrict__ g1, const float* __restrict__ be1,
    const float* __restrict__ m1, const float* __restrict__ v1,
    const float* __restrict__ w2, const float* __restrict__ b2,
    const float* __restrict__ g2, const float* __restrict__ be2,
    const float* __restrict__ m2, const float* __restrict__ v2,
    float* __restrict__ out)
{
  __shared__ __align__(16) float Xf[2048];
  __shared__ __align__(16) float Hf[2048];
  __shared__ float scl[128];
  __shared__ float bia[128];
  __shared__ int   nIx[32];
  __shared__ __align__(8) uint2 Lr[128];

  const int t  = threadIdx.x;
  const int bs = blockIdx.x;
  const int b  = bs >> 11;
  const int lane = t & 63, wv = t >> 6;
  const int quad = lane >> 4, mcol = lane & 15;

  if (t < 128) Lr[t] = pw[(size_t)bs * (SPLIT_*32) + t];
  if (t >= 128) {
    int i = t - 128;
    float sc = g0[i] * rsqrtf(v0[i] + 1e-5f);
    scl[i] = sc;
    bia[i] = (b0[i] - m0[i]) * sc + be0[i];
  }
  __syncthreads();
  if (t < 128) {
    uint2 e = Lr[t];
    float ev = __uint_as_float(e.x);
    int rank = t & 31;
    #pragma unroll
    for (int oq = 1; oq < 4; ++oq) {
      const uint2* L = Lr + ((((t >> 5) + oq) & 3) << 5);
      int lo = 0;
      #pragma unroll
      for (int stp = 16; stp > 0; stp >>= 1) {
        uint2 c = L[lo + stp - 1];
        float cv = __uint_as_float(c.x);
        bool lt = (cv < ev) || (cv == ev && c.y < e.y);
        lo += lt ? stp : 0;
      }
      {
        uint2 c = L[lo];
        float cv = __uint_as_float(c.x);
        bool lt = (cv < ev) || (cv == ev && c.y < e.y);
        lo += lt ? 1 : 0;
      }
      rank += lo;
    }
    if (rank < 32) nIx[rank] = (int)e.y;
  }
  __syncthreads();
  #pragma unroll
  for (int rep = 0; rep < 2; ++rep) {
    int task = rep*256 + t;
    int row = task >> 4, j4 = task & 15;
    float4 v = *(const float4*)(points + ((size_t)b*N_ + nIx[row])*64 + j4*4);
    int kt = j4 >> 3, qk = (j4 >> 1) & 3, h = j4 & 1;
    *(float4*)(Xf + (((row>>4)*2 + kt)*2 + h)*256 + (qk*16 + (row&15))*4) = v;
  }
  __syncthreads();

  layer_mfma(lane, wv, Xf, Hf, w0, scl, bia);
  __syncthreads();
  if (t < 64) {
    float sc = g1[t] * rsqrtf(v1[t] + 1e-5f);
    scl[t] = sc;
    bia[t] = (b1[t] - m1[t]) * sc + be1[t];
  }
  __syncthreads();
  layer_mfma(lane, wv, Hf, Xf, w1, scl, bia);
  __syncthreads();
  if (t < 128) {
    float sc = g2[t] * rsqrtf(v2[t] + 1e-5f);
    scl[t] = sc;
    bia[t] = (b2[t] - m2[t]) * sc + be2[t];
  }
  __syncthreads();

  short8_ A0[2][2], A1[2][2];
  #pragma unroll
  for (int mt = 0; mt < 2; ++mt)
    #pragma unroll
    for (int kt = 0; kt < 2; ++kt) {
      float4 x0 = *(const float4*)(Xf + (((mt*2+kt)*2+0)*256) + lane*4);
      float4 x1 = *(const float4*)(Xf + (((mt*2+kt)*2+1)*256) + lane*4);
      float f[8] = {x0.x,x0.y,x0.z,x0.w, x1.x,x1.y,x1.z,x1.w};
      bf2split8(f, A0[mt][kt], A1[mt][kt]);
    }
  float* outp = out + (size_t)(B_*S_)*3 + (size_t)bs*128;
  #pragma unroll
  for (int sub = 0; sub < 2; ++sub) {
    const int o = (wv*2 + sub)*16 + mcol;
    const float sc = scl[o];
    short8_ B0[2], B1[2];
    #pragma unroll
    for (int kt = 0; kt < 2; ++kt) {
      const float* wp = w2 + o*64 + kt*32 + quad*8;
      float4 u0 = *(const float4*)(wp);
      float4 u1 = *(const float4*)(wp + 4);
      float f[8] = {u0.x*sc,u0.y*sc,u0.z*sc,u0.w*sc,
                    u1.x*sc,u1.y*sc,u1.z*sc,u1.w*sc};
      bf2split8(f, B0[kt], B1[kt]);
    }
    float vmax = -3.0e38f;
    #pragma unroll
    for (int mt = 0; mt < 2; ++mt) {
      f32x4_ a = {0.f, 0.f, 0.f, 0.f};
      #pragma unroll
      for (int kt = 0; kt < 2; ++kt) {
        a = __builtin_amdgcn_mfma_f32_16x16x32_bf16(A0[mt][kt], B0[kt], a, 0,0,0);
        a = __builtin_amdgcn_mfma_f32_16x16x32_bf16(A0[mt][kt], B1[kt], a, 0,0,0);
        a = __builtin_amdgcn_mfma_f32_16x16x32_bf16(A1[mt][kt], B0[kt], a, 0,0,0);
      }
      vmax = fmaxf(vmax, fmaxf(fmaxf(a[0], a[1]), fmaxf(a[2], a[3])));
    }
    vmax = fmaxf(vmax, __shfl_xor(vmax, 16));
    vmax = fmaxf(vmax, __shfl_xor(vmax, 32));
    if (quad == 0) outp[o] = fmaxf(vmax + bia[o], 0.f);
  }
}

// =====================================================================
extern "C" void kernel_launch(void* const* d_in, const int* in_sizes, int n_in,
                              void* d_out, int out_size, void* d_ws, size_t ws_size,
                              hipStream_t stream)
{
  const float* xyz  = (const float*)d_in[0];
  const float* pts  = (const float*)d_in[1];
  const int*   sidx = (const int*)  d_in[2];
  const float* w0 = (const float*)d_in[3];
  const float* b0 = (const float*)d_in[4];
  const float* g0 = (const float*)d_in[5];
  const float* be0= (const float*)d_in[6];
  const float* m0 = (const float*)d_in[7];
  const float* v0 = (const float*)d_in[8];
  const float* w1 = (const float*)d_in[9];
  const float* b1 = (const float*)d_in[10];
  const float* g1 = (const float*)d_in[11];
  const float* be1= (const float*)d_in[12];
  const float* m1 = (const float*)d_in[13];
  const float* v1 = (const float*)d_in[14];
  const float* w2 = (const float*)d_in[15];
  const float* b2 = (const float*)d_in[16];
  const float* g2 = (const float*)d_in[17];
  const float* be2= (const float*)d_in[18];
  const float* m2 = (const float*)d_in[19];
  const float* v2 = (const float*)d_in[20];

  float* out = (float*)d_out;
  // ws: sqn (512KB) | Ws/bias region (2MB, ex-nbr) | pw (16.8MB) | planes
  float* sqn = (float*)d_ws;
  char*  nb  = (char*)d_ws + (size_t)B_*N_*4;
  short* Ws0_0 = (short*)nb;
  short* Ws0_1 = Ws0_0 + 4096;
  short* Ws1_0 = Ws0_1 + 4096;
  short* Ws1_1 = Ws1_0 + 4096;
  short* Ws2_0 = Ws1_1 + 4096;
  short* Ws2_1 = Ws2_0 + 8192;
  float* bia0  = (float*)(Ws2_1 + 8192);
  float* bia1  = bia0 + 64;
  float* bia2  = bia1 + 64;
  uint2* pw  = (uint2*)((char*)d_ws + (size_t)B_*N_*4 + (size_t)B_*S_*K_*4);
  char*  pl  = (char*)d_ws + (size_t)B_*N_*4 + (size_t)B_*S_*K_*4
             + (size_t)B_*S_*SPLIT_*32*8;
  short* P0 = (short*)pl;
  short* P1 = P0 + PLANE_;
  short* P2 = P1 + PLANE_;
  const size_t need = (size_t)B_*N_*4 + (size_t)B_*S_*K_*4
                    + (size_t)B_*S_*SPLIT_*32*8 + 3*PLANE_*2;

  if (ws_size >= need) {
    k_prep<<<(B_*N_)/256, 256, 0, stream>>>(xyz, pts, sidx, out, sqn, P0, P1, P2,
              w0,b0,g0,be0,m0,v0, w1,b1,g1,be1,m1,v1, w2,b2,g2,be2,m2,v2,
              Ws0_0,Ws0_1, Ws1_0,Ws1_1, Ws2_0,Ws2_1, bia0,bia1,bia2);
    k_knn <<<B_*32*SPLIT_, 256, 0, stream>>>(P0, P1, P2, sidx, sqn, pw);
    k_mlp <<<B_*S_, 256, 0, stream>>>(pts, pw,
              Ws0_0,Ws0_1, Ws1_0,Ws1_1, Ws2_0,Ws2_1, bia0,bia1,bia2, out);
  } else {
    k_prep_fb<<<(B_*N_)/256, 256, 0, stream>>>(xyz, pts, sidx, out, sqn);
    k_knn_fb <<<B_*32*SPLIT_, 256, 0, stream>>>(pts, sidx, sqn, pw);
    k_mlp_fb <<<B_*S_, 256, 0, stream>>>(pts, pw,
              w0,b0,g0,be0,m0,v0, w1,b1,g1,be1,m1,v1, w2,b2,g2,be2,m2,v2, out);
  }
}